// Round 7
// baseline (394.719 us; speedup 1.0000x reference)
//
#include <hip/hip_runtime.h>
#include <cstdint>
#include <cstddef>

#define TT 8

#define H1_ELEMS (128*32*20*20)   // 1,638,400
#define E2_ELEMS (128*64*81)      // 663,552
#define E3_ELEMS (128*64*49)      // 401,408

// ---------------- merged weight transpose prep (wT1 + wT2 + wT3) ----------------
__global__ void prep_wT123(const float* __restrict__ w1, const float* __restrict__ w2,
                           const float* __restrict__ w3, float* __restrict__ wT1,
                           float* __restrict__ wT2, float* __restrict__ wT3) {
  int i = blockIdx.x * 256 + threadIdx.x;
  if (i < 8192) {                                   // 32 oc x 256 pos
    int oc = i >> 8, pos = i & 255;
    wT1[pos * 32 + oc] = w1[oc * 256 + pos];
  } else if (i < 40960) {                           // 64 oc x 512 pos
    int j = i - 8192;
    int oc = j & 63, pos = j >> 6;
    wT2[pos * 64 + oc] = w2[oc * 512 + pos];
  } else if (i < 77824) {                           // 64 oc x 576 pos
    int j = i - 40960;
    int oc = j & 63, pos = j >> 6;
    wT3[pos * 64 + oc] = w3[oc * 576 + pos];
  }
}

// tiled transpose: w[512][3136] -> wT[3136][512]
__global__ void prep_wTf(const float* __restrict__ w, float* __restrict__ wT) {
  __shared__ float tile[32][33];
  int k0 = blockIdx.x * 32;
  int o0 = blockIdx.y * 32;
  int tx = threadIdx.x & 31, ty = threadIdx.x >> 5;
  #pragma unroll
  for (int j = 0; j < 4; j++)
    tile[ty + j * 8][tx] = w[(size_t)(o0 + ty + j * 8) * 3136 + k0 + tx];
  __syncthreads();
  #pragma unroll
  for (int j = 0; j < 4; j++)
    wT[(size_t)(k0 + ty + j * 8) * 512 + o0 + tx] = tile[tx][ty + j * 8];
}

// ---------------- conv1: [128,4,84,84] -> [128,32,20,20], k8 s4 ----------------
__global__ __launch_bounds__(256) void k_conv1(const float* __restrict__ x,
                                               const float* __restrict__ wT,
                                               const float* __restrict__ bias,
                                               float* __restrict__ out) {
  __shared__ float xt[14784];                       // 59,136 B
  int tid = threadIdx.x;
  int img  = blockIdx.x >> 1;
  int half = blockIdx.x & 1;
  float4* dst = (float4*)xt;
  #pragma unroll
  for (int ci = 0; ci < 4; ci++) {
    const float4* s4 = (const float4*)(x + (size_t)img * 28224 + ci * 7056 + half * 3360);
    for (int i = tid; i < 924; i += 256) dst[ci * 924 + i] = s4[i];
  }
  __syncthreads();
  if (tid >= 200) return;
  int oyl = tid / 20, ox = tid % 20;
  float acc[32];
  #pragma unroll
  for (int j = 0; j < 32; j++) acc[j] = 0.f;
  int xb0 = oyl * 336 + ox * 4;
  #pragma unroll 1
  for (int ci = 0; ci < 4; ci++) {
    #pragma unroll 1
    for (int ky = 0; ky < 8; ky++) {
      const float* xr = xt + ci * 3696 + xb0 + ky * 84;
      float4 xa  = *(const float4*)xr;
      float4 xbv = *(const float4*)(xr + 4);
      const float* wr = wT + (ci * 8 + ky) * 256;   // wave-uniform -> s_load
      float xs[8] = {xa.x, xa.y, xa.z, xa.w, xbv.x, xbv.y, xbv.z, xbv.w};
      #pragma unroll
      for (int kx = 0; kx < 8; kx++) {
        #pragma unroll
        for (int j = 0; j < 32; j++)
          acc[j] = fmaf(xs[kx], wr[kx * 32 + j], acc[j]);
      }
    }
  }
  size_t obase = (size_t)img * 12800 + (half * 10 + oyl) * 20 + ox;
  #pragma unroll
  for (int j = 0; j < 32; j++) out[obase + j * 400] = acc[j] + bias[j];
}

// ---------------- BN stats, two-stage ----------------
template <int HW>
__global__ void k_bnpartial(const float* __restrict__ xp, int C, int Nper,
                            float* __restrict__ pout) {
  int c = blockIdx.x, s = blockIdx.y, S = gridDim.y, tid = threadIdx.x;
  int n = Nper * HW;
  float sum = 0.f, sum2 = 0.f;
  for (int i = tid; i < n; i += 256) {
    int nb = s * Nper + i / HW;
    int p  = i % HW;
    float v = xp[((size_t)nb * C + c) * HW + p];
    sum += v; sum2 += v * v;
  }
  __shared__ float l0[256], l1[256];
  l0[tid] = sum; l1[tid] = sum2; __syncthreads();
  for (int k = 128; k > 0; k >>= 1) {
    if (tid < k) { l0[tid] += l0[tid + k]; l1[tid] += l1[tid + k]; }
    __syncthreads();
  }
  if (tid == 0) { pout[(c * S + s) * 2] = l0[0]; pout[(c * S + s) * 2 + 1] = l1[0]; }
}

__global__ void k_bnfinal(const float* __restrict__ pin, int S, float n,
                          float* __restrict__ meanArr, float* __restrict__ rstdArr) {
  int c = blockIdx.x, lane = threadIdx.x;
  float s = 0.f, s2 = 0.f;
  if (lane < S) { s = pin[(c * S + lane) * 2]; s2 = pin[(c * S + lane) * 2 + 1]; }
  for (int off = 8; off > 0; off >>= 1) { s += __shfl_down(s, off); s2 += __shfl_down(s2, off); }
  if (lane == 0) {
    float m = s / n;
    float var = s2 / n - m * m;
    meanArr[c] = m;
    rstdArr[c] = rsqrtf(var + 1e-5f);
  }
}

// ---------------- BN + LIF stage 1 -> bit-packed spikes ----------------
__global__ void k_lif1b(const float* __restrict__ h, const float* __restrict__ mean,
                        const float* __restrict__ rstd, const float* __restrict__ g,
                        const float* __restrict__ bb, uint32_t* __restrict__ sout) {
  int idx = blockIdx.x * 256 + threadIdx.x;         // < 81920 = (img*32+ci)*20+row
  int ic = idx / 20;
  int ci = ic & 31;
  const float* hp = h + (size_t)idx * 20;
  float gm = g[ci], mm = mean[ci], rs = rstd[ci], bc = bb[ci];
  float xv[20];
  #pragma unroll
  for (int j4 = 0; j4 < 5; j4++) {
    float4 hv = ((const float4*)hp)[j4];
    xv[j4 * 4 + 0] = gm * (hv.x - mm) * rs + bc;
    xv[j4 * 4 + 1] = gm * (hv.y - mm) * rs + bc;
    xv[j4 * 4 + 2] = gm * (hv.z - mm) * rs + bc;
    xv[j4 * 4 + 3] = gm * (hv.w - mm) * rs + bc;
  }
  float v[20];
  #pragma unroll
  for (int j = 0; j < 20; j++) v[j] = 0.f;
  #pragma unroll
  for (int t = 0; t < TT; t++) {
    uint32_t w = 0;
    #pragma unroll
    for (int j = 0; j < 20; j++) {
      v[j] = v[j] + (xv[j] - v[j]) * 0.5f;
      uint32_t s = (v[j] >= 1.0f);
      w |= s << j;
      if (s) v[j] = 0.f;
    }
    sout[t * 81920 + idx] = w;
  }
}

// ---------------- BN + LIF generic -> bit-packed (x differs per t) ----------------
template <int W, int NROW>
__global__ void k_lifb(const float* __restrict__ h, const float* __restrict__ mean,
                       const float* __restrict__ rstd, const float* __restrict__ g,
                       const float* __restrict__ bb, uint32_t* __restrict__ sout,
                       int E) {
  int idx = blockIdx.x * 256 + threadIdx.x;
  int bc = idx / NROW;
  int c = bc & 63;
  float gm = g[c], mm = mean[c], rs = rstd[c], bcn = bb[c];
  float v[W];
  #pragma unroll
  for (int j = 0; j < W; j++) v[j] = 0.f;
  int nword = 128 * 64 * NROW;
  #pragma unroll
  for (int t = 0; t < TT; t++) {
    const float* hp = h + (size_t)t * E + (size_t)idx * W;
    uint32_t w = 0;
    #pragma unroll
    for (int j = 0; j < W; j++) {
      float xv = gm * (hp[j] - mm) * rs + bcn;
      v[j] = v[j] + (xv - v[j]) * 0.5f;
      uint32_t s = (v[j] >= 1.0f);
      w |= s << j;
      if (s) v[j] = 0.f;
    }
    sout[t * nword + idx] = w;
  }
}

// ---------------- conv2: bit spikes -> [1024,64,9,9], k4 s2 ----------------
// grid (171 six-image-groups, 4 oc-quarters), 256 thr; thread = (px, img-pair i/i+3)
__global__ __launch_bounds__(256) void k_conv2b(const uint32_t* __restrict__ s1b,
                                                const float* __restrict__ wT,
                                                const float* __restrict__ bias,
                                                float* __restrict__ out) {
  __shared__ uint32_t sb[3840];                     // 6 img x 640 words
  int tid = threadIdx.x;
  int img0 = blockIdx.x * 6;
  int q = blockIdx.y;
  int nImg = 1024 - img0; if (nImg > 6) nImg = 6;
  int nw = nImg * 640;
  const uint32_t* src = s1b + (size_t)img0 * 640;
  for (int i = tid; i < nw; i += 256) sb[i] = src[i];
  __syncthreads();
  if (tid >= 243) return;
  int li = tid / 81;                                // 0..2
  int p  = tid - li * 81;
  bool okB = (li + 3) < nImg;                       // img A always valid (img0<=1020, li<=2)
  int oy = p / 9, ox = p - oy * 9;
  int sh = ox * 2;
  float4 accA[4] = {}, accB[4] = {};
  const float* wq = wT + q * 16;
  const uint32_t* sbA = sb + li * 640 + oy * 2;
  const uint32_t* sbB = sbA + 3 * 640;
  #pragma unroll 2
  for (int ci = 0; ci < 32; ci++) {
    const uint32_t* rA = sbA + ci * 20;
    const uint32_t* rB = sbB + ci * 20;
    uint32_t wkA[4] = {rA[0], rA[1], rA[2], rA[3]};
    uint32_t wkB[4] = {rB[0], rB[1], rB[2], rB[3]};
    const float* w0 = wq + ci * 1024;
    #pragma unroll
    for (int ky = 0; ky < 4; ky++) {
      uint32_t bA = wkA[ky] >> sh;
      uint32_t bB = wkB[ky] >> sh;
      float svA[4], svB[4];
      svA[0] = (float)(bA & 1u);        svB[0] = (float)(bB & 1u);
      svA[1] = (float)((bA >> 1) & 1u); svB[1] = (float)((bB >> 1) & 1u);
      svA[2] = (float)((bA >> 2) & 1u); svB[2] = (float)((bB >> 2) & 1u);
      svA[3] = (float)((bA >> 3) & 1u); svB[3] = (float)((bB >> 3) & 1u);
      const float* wr = w0 + ky * 256;
      #pragma unroll
      for (int kx = 0; kx < 4; kx++) {
        const float* wp = wr + kx * 64;
        #pragma unroll
        for (int j = 0; j < 4; j++) {
          float4 wv = ((const float4*)wp)[j];
          accA[j].x = fmaf(svA[kx], wv.x, accA[j].x);
          accA[j].y = fmaf(svA[kx], wv.y, accA[j].y);
          accA[j].z = fmaf(svA[kx], wv.z, accA[j].z);
          accA[j].w = fmaf(svA[kx], wv.w, accA[j].w);
          accB[j].x = fmaf(svB[kx], wv.x, accB[j].x);
          accB[j].y = fmaf(svB[kx], wv.y, accB[j].y);
          accB[j].z = fmaf(svB[kx], wv.z, accB[j].z);
          accB[j].w = fmaf(svB[kx], wv.w, accB[j].w);
        }
      }
    }
  }
  size_t obA = ((size_t)(img0 + li) * 64 + q * 16) * 81 + p;
  #pragma unroll
  for (int j = 0; j < 4; j++) {
    out[obA + (j * 4 + 0) * 81] = accA[j].x + bias[q * 16 + j * 4 + 0];
    out[obA + (j * 4 + 1) * 81] = accA[j].y + bias[q * 16 + j * 4 + 1];
    out[obA + (j * 4 + 2) * 81] = accA[j].z + bias[q * 16 + j * 4 + 2];
    out[obA + (j * 4 + 3) * 81] = accA[j].w + bias[q * 16 + j * 4 + 3];
  }
  if (okB) {
    size_t obB = ((size_t)(img0 + li + 3) * 64 + q * 16) * 81 + p;
    #pragma unroll
    for (int j = 0; j < 4; j++) {
      out[obB + (j * 4 + 0) * 81] = accB[j].x + bias[q * 16 + j * 4 + 0];
      out[obB + (j * 4 + 1) * 81] = accB[j].y + bias[q * 16 + j * 4 + 1];
      out[obB + (j * 4 + 2) * 81] = accB[j].z + bias[q * 16 + j * 4 + 2];
      out[obB + (j * 4 + 3) * 81] = accB[j].w + bias[q * 16 + j * 4 + 3];
    }
  }
}

// ---------------- conv3: bit spikes [n][64ch][9row] -> [1024,64,7,7], k3 s1 ----
__global__ __launch_bounds__(256) void k_conv3b(const uint32_t* __restrict__ s2b,
                                                const float* __restrict__ wT,
                                                const float* __restrict__ bias,
                                                float* __restrict__ out) {
  __shared__ uint32_t sb[2880];
  int tid = threadIdx.x;
  int img0 = blockIdx.x * 5;
  int q = blockIdx.y;
  int liMax = 1024 - img0; if (liMax > 5) liMax = 5;
  int nw = liMax * 576;
  const uint32_t* src = s2b + (size_t)img0 * 576;
  for (int i = tid; i < nw; i += 256) sb[i] = src[i];
  __syncthreads();
  int li = tid / 49;
  int p  = tid - li * 49;
  if (li >= liMax) return;
  int oy = p / 7, ox = p - oy * 7;
  float4 acc[4] = {};
  const float* wq = wT + q * 16;
  const uint32_t* sbase = sb + li * 576 + oy;
  #pragma unroll 2
  for (int ci = 0; ci < 64; ci++) {
    const uint32_t* wrow = sbase + ci * 9;
    uint32_t wk0 = wrow[0], wk1 = wrow[1], wk2 = wrow[2];
    uint32_t wks[3] = {wk0, wk1, wk2};
    const float* w0 = wq + ci * 576;
    #pragma unroll
    for (int ky = 0; ky < 3; ky++) {
      uint32_t bits = wks[ky] >> ox;
      float sv[3];
      sv[0] = (float)(bits & 1u);
      sv[1] = (float)((bits >> 1) & 1u);
      sv[2] = (float)((bits >> 2) & 1u);
      const float* wr = w0 + ky * 192;
      #pragma unroll
      for (int kx = 0; kx < 3; kx++) {
        const float* wp = wr + kx * 64;
        #pragma unroll
        for (int j = 0; j < 4; j++) {
          float4 wv = ((const float4*)wp)[j];
          acc[j].x = fmaf(sv[kx], wv.x, acc[j].x);
          acc[j].y = fmaf(sv[kx], wv.y, acc[j].y);
          acc[j].z = fmaf(sv[kx], wv.z, acc[j].z);
          acc[j].w = fmaf(sv[kx], wv.w, acc[j].w);
        }
      }
    }
  }
  size_t obase = ((size_t)(img0 + li) * 64 + q * 16) * 49 + p;
  #pragma unroll
  for (int j = 0; j < 4; j++) {
    out[obase + (j * 4 + 0) * 49] = acc[j].x + bias[q * 16 + j * 4 + 0];
    out[obase + (j * 4 + 1) * 49] = acc[j].y + bias[q * 16 + j * 4 + 1];
    out[obase + (j * 4 + 2) * 49] = acc[j].z + bias[q * 16 + j * 4 + 2];
    out[obase + (j * 4 + 3) * 49] = acc[j].w + bias[q * 16 + j * 4 + 3];
  }
}

// ---------------- fc1: bit spikes [1024][64ch][7row] x wT[3136,512] -> part ----
__global__ __launch_bounds__(256) void k_fc1(const uint32_t* __restrict__ s3b,
                                             const float* __restrict__ wT,
                                             float* __restrict__ part) {
  __shared__ float xs[16 * 196];
  int tid = threadIdx.x;
  int rowblk = blockIdx.x >> 4;
  int kc     = blockIdx.x & 15;
  int row0 = rowblk * 16;
  int kb   = kc * 196;
  for (int i = tid; i < 448; i += 256) {            // 16r x 4c x 7row words
    int r = i / 28, rem = i - r * 28;
    int c = rem / 7, row = rem - c * 7;
    uint32_t w = s3b[(size_t)(row0 + r) * 448 + (kc * 4 + c) * 7 + row];
    int base = r * 196 + c * 49 + row * 7;
    #pragma unroll
    for (int xq = 0; xq < 7; xq++)
      xs[base + xq] = (float)((w >> xq) & 1u);
  }
  __syncthreads();
  int oc2 = tid * 2;
  float2 acc[16];
  #pragma unroll
  for (int r = 0; r < 16; r++) { acc[r].x = 0.f; acc[r].y = 0.f; }
  const float* wp = wT + (size_t)kb * 512 + oc2;
  const float4* xs4 = (const float4*)xs;
  for (int k4 = 0; k4 < 49; k4++) {
    float2 w0 = *(const float2*)(wp + (size_t)(k4 * 4 + 0) * 512);
    float2 w1 = *(const float2*)(wp + (size_t)(k4 * 4 + 1) * 512);
    float2 w2 = *(const float2*)(wp + (size_t)(k4 * 4 + 2) * 512);
    float2 w3 = *(const float2*)(wp + (size_t)(k4 * 4 + 3) * 512);
    #pragma unroll
    for (int r = 0; r < 16; r++) {
      float4 xv = xs4[r * 49 + k4];
      acc[r].x = fmaf(xv.x, w0.x, acc[r].x);  acc[r].y = fmaf(xv.x, w0.y, acc[r].y);
      acc[r].x = fmaf(xv.y, w1.x, acc[r].x);  acc[r].y = fmaf(xv.y, w1.y, acc[r].y);
      acc[r].x = fmaf(xv.z, w2.x, acc[r].x);  acc[r].y = fmaf(xv.z, w2.y, acc[r].y);
      acc[r].x = fmaf(xv.w, w3.x, acc[r].x);  acc[r].y = fmaf(xv.w, w3.y, acc[r].y);
    }
  }
  #pragma unroll
  for (int r = 0; r < 16; r++) {
    float* o = part + (size_t)kc * 524288 + (size_t)(row0 + r) * 512 + oc2;
    o[0] = acc[r].x; o[1] = acc[r].y;
  }
}

// ---------------- fused: 16-way partial reduce + bias + LIF -> hid u8 ----------
__global__ void k_fc1red_lif(const float* __restrict__ part, const float* __restrict__ bias,
                             unsigned char* __restrict__ hid) {
  int idx = blockIdx.x * 256 + threadIdx.x;
  float bv = bias[idx & 511];
  float v = 0.f;
  #pragma unroll
  for (int t = 0; t < TT; t++) {
    float a = part[t * 65536 + idx];
    #pragma unroll
    for (int j = 1; j < 16; j++) a += part[(size_t)j * 524288 + t * 65536 + idx];
    a += bv;
    v = v + (a - v) * 0.5f;
    unsigned char s = (v >= 1.0f);
    hid[t * 65536 + idx] = s;
    if (s) v = 0.f;
  }
}

// ---------------- fco + mean over T: [8,128,512](u8) -> [128,2] ----------------
__global__ void k_fco(const unsigned char* __restrict__ hid, const float* __restrict__ w,
                      const float* __restrict__ bias, float* __restrict__ out) {
  int b = blockIdx.x, tid = threadIdx.x;
  float a0 = 0.f, a1 = 0.f;
  for (int t = 0; t < TT; t++) {
    const unsigned char* hrow = hid + ((size_t)t * 128 + b) * 512;
    for (int o = tid; o < 512; o += 256) {
      if (hrow[o]) { a0 += w[o]; a1 += w[512 + o]; }
    }
  }
  __shared__ float l0[256], l1[256];
  l0[tid] = a0; l1[tid] = a1; __syncthreads();
  for (int k = 128; k > 0; k >>= 1) {
    if (tid < k) { l0[tid] += l0[tid + k]; l1[tid] += l1[tid + k]; }
    __syncthreads();
  }
  if (tid == 0) {
    out[b * 2 + 0] = l0[0] * 0.125f + bias[0];
    out[b * 2 + 1] = l1[0] * 0.125f + bias[1];
  }
}

extern "C" void kernel_launch(void* const* d_in, const int* in_sizes, int n_in,
                              void* d_out, int out_size, void* d_ws, size_t ws_size,
                              hipStream_t stream) {
  const float* x    = (const float*)d_in[0];
  const float* c1w  = (const float*)d_in[1];
  const float* c1b  = (const float*)d_in[2];
  const float* bn1g = (const float*)d_in[3];
  const float* bn1b = (const float*)d_in[4];
  const float* c2w  = (const float*)d_in[5];
  const float* c2b  = (const float*)d_in[6];
  const float* bn2g = (const float*)d_in[7];
  const float* bn2b = (const float*)d_in[8];
  const float* c3w  = (const float*)d_in[9];
  const float* c3b  = (const float*)d_in[10];
  const float* bn3g = (const float*)d_in[11];
  const float* bn3b = (const float*)d_in[12];
  const float* fc1w = (const float*)d_in[13];
  const float* fc1b = (const float*)d_in[14];
  const float* fcow = (const float*)d_in[15];
  const float* fcob = (const float*)d_in[16];
  float* out = (float*)d_out;

  char* ws = (char*)d_ws;
  // workspace (64.9 MB footprint)
  float*    h1     = (float*)(ws + 0);                 //  6,553,600 (dead after lif1b)
  uint32_t* s1bits = (uint32_t*)(ws + 6553600);        //  2,621,440 (dead after conv2b)
  float*    h2     = (float*)(ws + 19660800);          // 21,233,664 (dead after lif2b)
  uint32_t* s2bits = (uint32_t*)(ws + 40894464);       //  2,359,296 (dead after conv3b)
  float*    h3     = (float*)(ws + 46202880);          // 12,845,056 (dead after lif3b)
  uint32_t* s3bits = (uint32_t*)(ws + 59047936);       //  1,835,008
  unsigned char* hid = (unsigned char*)(ws + 64356352);//    524,288
  float*    st     = (float*)(ws + 64880640);          //      1,280
  // persistent small weights (region 62,259,200 .. 62,570,496)
  float* wT2    = (float*)(ws + 62259200);  // 131,072
  float* wT1    = (float*)(ws + 62390272);  // 32,768
  float* wT3    = (float*)(ws + 62423040);  // 147,456
  // overlays (lifetimes disjoint):
  float* wTf    = (float*)(ws + 0);         // 6,422,528 in h1 region (after lif1b)
  float* bnpart = (float*)(ws + 9437184);   // 8,192    in s1 region, past s1bits end
  float* f1part = (float*)(ws + 19660800);  // 33,554,432 spans dead h2+s2+h3 (fc1 time)

  prep_wT123<<<304, 256, 0, stream>>>(c1w, c2w, c3w, wT1, wT2, wT3);
  k_conv1  <<<256, 256, 0, stream>>>(x, wT1, c1b, h1);
  k_bnpartial<400><<<dim3(32, 16), 256, 0, stream>>>(h1, 32, 8, bnpart);
  k_bnfinal<<<32, 64, 0, stream>>>(bnpart, 16, 128.f * 400.f, st, st + 32);
  k_lif1b  <<<320, 256, 0, stream>>>(h1, st, st + 32, bn1g, bn1b, s1bits);
  prep_wTf <<<dim3(98, 16), 256, 0, stream>>>(fc1w, wTf);   // h1 region now free

  k_conv2b <<<dim3(171, 4), 256, 0, stream>>>(s1bits, wT2, c2b, h2);
  k_bnpartial<81><<<dim3(64, 16), 256, 0, stream>>>(h2, 64, 64, bnpart);
  k_bnfinal<<<64, 64, 0, stream>>>(bnpart, 16, 1024.f * 81.f, st + 64, st + 128);
  k_lifb<9, 9><<<288, 256, 0, stream>>>(h2, st + 64, st + 128, bn2g, bn2b, s2bits, E2_ELEMS);

  k_conv3b <<<dim3(205, 4), 256, 0, stream>>>(s2bits, wT3, c3b, h3);
  k_bnpartial<49><<<dim3(64, 16), 256, 0, stream>>>(h3, 64, 64, bnpart);
  k_bnfinal<<<64, 64, 0, stream>>>(bnpart, 16, 1024.f * 49.f, st + 192, st + 256);
  k_lifb<7, 7><<<224, 256, 0, stream>>>(h3, st + 192, st + 256, bn3g, bn3b, s3bits, E3_ELEMS);

  k_fc1    <<<1024, 256, 0, stream>>>(s3bits, wTf, f1part); // h2/s2/h3 now free
  k_fc1red_lif<<<256, 256, 0, stream>>>(f1part, fc1b, hid);
  k_fco    <<<128, 256, 0, stream>>>(hid, fcow, fcob, out);
}

// Round 8
// 346.906 us; speedup vs baseline: 1.1378x; 1.1378x over previous
//
#include <hip/hip_runtime.h>
#include <cstdint>
#include <cstddef>

#define TT 8

#define H1_ELEMS (128*32*20*20)   // 1,638,400
#define E2_ELEMS (128*64*81)      // 663,552
#define E3_ELEMS (128*64*49)      // 401,408

typedef __attribute__((ext_vector_type(8))) short short8;
typedef __attribute__((ext_vector_type(4))) float f32x4;

// ---------------- weight transpose prep (wT1 + wT3) ----------------
__global__ void prep_wT13(const float* __restrict__ w1, const float* __restrict__ w3,
                          float* __restrict__ wT1, float* __restrict__ wT3) {
  int i = blockIdx.x * 256 + threadIdx.x;
  if (i < 8192) {                                   // 32 oc x 256 pos
    int oc = i >> 8, pos = i & 255;
    wT1[pos * 32 + oc] = w1[oc * 256 + pos];
  } else if (i < 45056) {                           // 64 oc x 576 pos
    int j = i - 8192;
    int oc = j & 63, pos = j >> 6;
    wT3[pos * 64 + oc] = w3[oc * 576 + pos];
  }
}

// ---------------- conv2 MFMA weight prep: fp32 -> exact 3x bf16 frag layout ----
// layout elem idx = (((term*16 + kstep)*4 + quad)*64 + oc)*8 + j ; k = kstep*32+quad*8+j
__global__ void prep_w2frag(const float* __restrict__ w2, __bf16* __restrict__ wf) {
  int i = blockIdx.x * 256 + threadIdx.x;
  if (i >= 98304) return;
  int j    = i & 7;
  int oc   = (i >> 3) & 63;
  int quad = (i >> 9) & 3;
  int ksg  = (i >> 11) & 15;
  int term = i >> 15;
  int k = ksg * 32 + quad * 8 + j;
  int ci = k >> 4, kpos = k & 15;
  float w = w2[oc * 512 + ci * 16 + kpos];
  float hf = (float)(__bf16)w;                      // exact 3-term split:
  float r1 = w - hf;                                // w == hi + mid + lo  (bitwise)
  float mf = (float)(__bf16)r1;
  float r2 = r1 - mf;
  __bf16 val = (term == 0) ? (__bf16)w : (term == 1) ? (__bf16)r1 : (__bf16)r2;
  wf[i] = val;
}

// tiled transpose: w[512][3136] -> wT[3136][512]
__global__ void prep_wTf(const float* __restrict__ w, float* __restrict__ wT) {
  __shared__ float tile[32][33];
  int k0 = blockIdx.x * 32;
  int o0 = blockIdx.y * 32;
  int tx = threadIdx.x & 31, ty = threadIdx.x >> 5;
  #pragma unroll
  for (int j = 0; j < 4; j++)
    tile[ty + j * 8][tx] = w[(size_t)(o0 + ty + j * 8) * 3136 + k0 + tx];
  __syncthreads();
  #pragma unroll
  for (int j = 0; j < 4; j++)
    wT[(size_t)(k0 + ty + j * 8) * 512 + o0 + tx] = tile[tx][ty + j * 8];
}

// ---------------- conv1: [128,4,84,84] -> [128,32,20,20], k8 s4 ----------------
__global__ __launch_bounds__(256) void k_conv1(const float* __restrict__ x,
                                               const float* __restrict__ wT,
                                               const float* __restrict__ bias,
                                               float* __restrict__ out) {
  __shared__ float xt[14784];                       // 59,136 B
  int tid = threadIdx.x;
  int img  = blockIdx.x >> 1;
  int half = blockIdx.x & 1;
  float4* dst = (float4*)xt;
  #pragma unroll
  for (int ci = 0; ci < 4; ci++) {
    const float4* s4 = (const float4*)(x + (size_t)img * 28224 + ci * 7056 + half * 3360);
    for (int i = tid; i < 924; i += 256) dst[ci * 924 + i] = s4[i];
  }
  __syncthreads();
  if (tid >= 200) return;
  int oyl = tid / 20, ox = tid % 20;
  float acc[32];
  #pragma unroll
  for (int j = 0; j < 32; j++) acc[j] = 0.f;
  int xb0 = oyl * 336 + ox * 4;
  #pragma unroll 1
  for (int ci = 0; ci < 4; ci++) {
    #pragma unroll 1
    for (int ky = 0; ky < 8; ky++) {
      const float* xr = xt + ci * 3696 + xb0 + ky * 84;
      float4 xa  = *(const float4*)xr;
      float4 xbv = *(const float4*)(xr + 4);
      const float* wr = wT + (ci * 8 + ky) * 256;   // wave-uniform -> s_load
      float xs[8] = {xa.x, xa.y, xa.z, xa.w, xbv.x, xbv.y, xbv.z, xbv.w};
      #pragma unroll
      for (int kx = 0; kx < 8; kx++) {
        #pragma unroll
        for (int j = 0; j < 32; j++)
          acc[j] = fmaf(xs[kx], wr[kx * 32 + j], acc[j]);
      }
    }
  }
  size_t obase = (size_t)img * 12800 + (half * 10 + oyl) * 20 + ox;
  #pragma unroll
  for (int j = 0; j < 32; j++) out[obase + j * 400] = acc[j] + bias[j];
}

// ---------------- BN stats, two-stage ----------------
template <int HW>
__global__ void k_bnpartial(const float* __restrict__ xp, int C, int Nper,
                            float* __restrict__ pout) {
  int c = blockIdx.x, s = blockIdx.y, S = gridDim.y, tid = threadIdx.x;
  int n = Nper * HW;
  float sum = 0.f, sum2 = 0.f;
  for (int i = tid; i < n; i += 256) {
    int nb = s * Nper + i / HW;
    int p  = i % HW;
    float v = xp[((size_t)nb * C + c) * HW + p];
    sum += v; sum2 += v * v;
  }
  __shared__ float l0[256], l1[256];
  l0[tid] = sum; l1[tid] = sum2; __syncthreads();
  for (int k = 128; k > 0; k >>= 1) {
    if (tid < k) { l0[tid] += l0[tid + k]; l1[tid] += l1[tid + k]; }
    __syncthreads();
  }
  if (tid == 0) { pout[(c * S + s) * 2] = l0[0]; pout[(c * S + s) * 2 + 1] = l1[0]; }
}

__global__ void k_bnfinal(const float* __restrict__ pin, int S, float n,
                          float* __restrict__ meanArr, float* __restrict__ rstdArr) {
  int c = blockIdx.x, lane = threadIdx.x;
  float s = 0.f, s2 = 0.f;
  if (lane < S) { s = pin[(c * S + lane) * 2]; s2 = pin[(c * S + lane) * 2 + 1]; }
  for (int off = 8; off > 0; off >>= 1) { s += __shfl_down(s, off); s2 += __shfl_down(s2, off); }
  if (lane == 0) {
    float m = s / n;
    float var = s2 / n - m * m;
    meanArr[c] = m;
    rstdArr[c] = rsqrtf(var + 1e-5f);
  }
}

// ---------------- BN + LIF stage 1 -> bit-packed spikes ----------------
__global__ void k_lif1b(const float* __restrict__ h, const float* __restrict__ mean,
                        const float* __restrict__ rstd, const float* __restrict__ g,
                        const float* __restrict__ bb, uint32_t* __restrict__ sout) {
  int idx = blockIdx.x * 256 + threadIdx.x;         // < 81920 = (img*32+ci)*20+row
  int ic = idx / 20;
  int ci = ic & 31;
  const float* hp = h + (size_t)idx * 20;
  float gm = g[ci], mm = mean[ci], rs = rstd[ci], bc = bb[ci];
  float xv[20];
  #pragma unroll
  for (int j4 = 0; j4 < 5; j4++) {
    float4 hv = ((const float4*)hp)[j4];
    xv[j4 * 4 + 0] = gm * (hv.x - mm) * rs + bc;
    xv[j4 * 4 + 1] = gm * (hv.y - mm) * rs + bc;
    xv[j4 * 4 + 2] = gm * (hv.z - mm) * rs + bc;
    xv[j4 * 4 + 3] = gm * (hv.w - mm) * rs + bc;
  }
  float v[20];
  #pragma unroll
  for (int j = 0; j < 20; j++) v[j] = 0.f;
  #pragma unroll
  for (int t = 0; t < TT; t++) {
    uint32_t w = 0;
    #pragma unroll
    for (int j = 0; j < 20; j++) {
      v[j] = v[j] + (xv[j] - v[j]) * 0.5f;
      uint32_t s = (v[j] >= 1.0f);
      w |= s << j;
      if (s) v[j] = 0.f;
    }
    sout[t * 81920 + idx] = w;
  }
}

// ---------------- BN + LIF generic -> bit-packed (x differs per t) ----------------
template <int W, int NROW>
__global__ void k_lifb(const float* __restrict__ h, const float* __restrict__ mean,
                       const float* __restrict__ rstd, const float* __restrict__ g,
                       const float* __restrict__ bb, uint32_t* __restrict__ sout,
                       int E) {
  int idx = blockIdx.x * 256 + threadIdx.x;
  int bc = idx / NROW;
  int c = bc & 63;
  float gm = g[c], mm = mean[c], rs = rstd[c], bcn = bb[c];
  float v[W];
  #pragma unroll
  for (int j = 0; j < W; j++) v[j] = 0.f;
  int nword = 128 * 64 * NROW;
  #pragma unroll
  for (int t = 0; t < TT; t++) {
    const float* hp = h + (size_t)t * E + (size_t)idx * W;
    uint32_t w = 0;
    #pragma unroll
    for (int j = 0; j < W; j++) {
      float xv = gm * (hp[j] - mm) * rs + bcn;
      v[j] = v[j] + (xv - v[j]) * 0.5f;
      uint32_t s = (v[j] >= 1.0f);
      w |= s << j;
      if (s) v[j] = 0.f;
    }
    sout[t * nword + idx] = w;
  }
}

// ---------------- conv2 via MFMA: C[96px][64oc] = S[96][512] x W[512][64] per img ----
// block = 2 imgs, 4 waves. wave: img_local = w>>1, px-tiles tg*3..tg*3+2, 64 oc, full K.
// mfma_f32_16x16x32_bf16:  A[m=lane&15][k=quad*8+j], B[k=quad*8+j][n=lane&15],
//                          C col=lane&15, row=quad*4+reg   (guide §3, m89/m120 verified)
__global__ __launch_bounds__(256) void k_conv2m(const uint32_t* __restrict__ s1b,
                                                const __bf16* __restrict__ wf,
                                                const float* __restrict__ bias,
                                                float* __restrict__ out) {
  __shared__ uint32_t sp[1280];                     // 2 img x 640 spike words
  __shared__ uint4 wl4[3072];                       // 49,152 B weight chunk
  __bf16* wl = (__bf16*)wl4;
  int tid = threadIdx.x;
  int img0 = blockIdx.x * 2;
  {
    const uint32_t* src = s1b + (size_t)img0 * 640;
    for (int i = tid; i < 1280; i += 256) sp[i] = src[i];
  }
  int wave = tid >> 6, lane = tid & 63;
  int img_local = wave >> 1;
  int tg = wave & 1;
  int l15 = lane & 15, quad = lane >> 4;
  int ci_off = quad >> 1;                           // which of 2 ci in a k-step
  int kyp = (quad & 1) * 2;                         // ky pair base
  int spb[3], sh[3];
  #pragma unroll
  for (int mt = 0; mt < 3; mt++) {
    int px = tg * 48 + mt * 16 + l15;
    if (px > 80) px = 80;                           // clamp pad lanes (stores masked)
    int oy = px / 9, ox = px - oy * 9;
    sh[mt]  = ox * 2;
    spb[mt] = img_local * 640 + ci_off * 20 + oy * 2 + kyp;
  }
  f32x4 acc[3][4];
  #pragma unroll
  for (int mt = 0; mt < 3; mt++)
    #pragma unroll
    for (int nt = 0; nt < 4; nt++) acc[mt][nt] = (f32x4){0.f, 0.f, 0.f, 0.f};

  for (int kc = 0; kc < 4; kc++) {
    __syncthreads();
    // stage weight chunk kc: 24576 bf16 (12 iters x 8 elems/thread)
    for (int o = tid * 8; o < 24576; o += 2048) {
      int tk = o >> 11;                             // term*4 + ksl
      int term = tk >> 2, ksl = tk & 3;
      const __bf16* src = wf + (((term * 16 + kc * 4 + ksl)) << 11) + (o & 2047);
      *(uint4*)(wl + o) = *(const uint4*)src;
    }
    __syncthreads();
    #pragma unroll
    for (int ks = 0; ks < 4; ks++) {
      int ksg = kc * 4 + ks;
      short8 a[3];
      #pragma unroll
      for (int mt = 0; mt < 3; mt++) {
        uint32_t w0 = sp[spb[mt] + ksg * 40];
        uint32_t w1 = sp[spb[mt] + ksg * 40 + 1];
        uint32_t n0 = (w0 >> sh[mt]) & 15u;
        uint32_t n1 = (w1 >> sh[mt]) & 15u;
        union { uint32_t u[4]; short8 v; } A;
        A.u[0] = ((n0 & 1u) ? 0x3F80u : 0u) | ((n0 & 2u) ? 0x3F800000u : 0u);
        A.u[1] = ((n0 & 4u) ? 0x3F80u : 0u) | ((n0 & 8u) ? 0x3F800000u : 0u);
        A.u[2] = ((n1 & 1u) ? 0x3F80u : 0u) | ((n1 & 2u) ? 0x3F800000u : 0u);
        A.u[3] = ((n1 & 4u) ? 0x3F80u : 0u) | ((n1 & 8u) ? 0x3F800000u : 0u);
        a[mt] = A.v;
      }
      #pragma unroll
      for (int term = 0; term < 3; term++) {
        int fb = ((term * 4 + ks) << 11) + (quad << 9);
        #pragma unroll
        for (int nt = 0; nt < 4; nt++) {
          short8 b = *(const short8*)(wl + fb + ((nt << 4) + l15) * 8);
          #pragma unroll
          for (int mt = 0; mt < 3; mt++)
            acc[mt][nt] = __builtin_amdgcn_mfma_f32_16x16x32_bf16(a[mt], b, acc[mt][nt], 0, 0, 0);
        }
      }
    }
  }
  // epilogue: C row = quad*4 + reg -> px, col = l15 -> oc (+ nt*16)
  #pragma unroll
  for (int nt = 0; nt < 4; nt++) {
    int oc = nt * 16 + l15;
    float bv = bias[oc];
    float* op = out + ((size_t)(img0 + img_local) * 64 + oc) * 81;
    #pragma unroll
    for (int mt = 0; mt < 3; mt++) {
      int pxr = tg * 48 + mt * 16 + quad * 4;
      #pragma unroll
      for (int r = 0; r < 4; r++) {
        int px = pxr + r;
        if (px < 81) op[px] = acc[mt][nt][r] + bv;
      }
    }
  }
}

// ---------------- conv3: bit spikes [n][64ch][9row] -> [1024,64,7,7], k3 s1 ----
__global__ __launch_bounds__(256) void k_conv3b(const uint32_t* __restrict__ s2b,
                                                const float* __restrict__ wT,
                                                const float* __restrict__ bias,
                                                float* __restrict__ out) {
  __shared__ uint32_t sb[2880];
  int tid = threadIdx.x;
  int img0 = blockIdx.x * 5;
  int q = blockIdx.y;
  int liMax = 1024 - img0; if (liMax > 5) liMax = 5;
  int nw = liMax * 576;
  const uint32_t* src = s2b + (size_t)img0 * 576;
  for (int i = tid; i < nw; i += 256) sb[i] = src[i];
  __syncthreads();
  int li = tid / 49;
  int p  = tid - li * 49;
  if (li >= liMax) return;
  int oy = p / 7, ox = p - oy * 7;
  float4 acc[4] = {};
  const float* wq = wT + q * 16;
  const uint32_t* sbase = sb + li * 576 + oy;
  #pragma unroll 2
  for (int ci = 0; ci < 64; ci++) {
    const uint32_t* wrow = sbase + ci * 9;
    uint32_t wk0 = wrow[0], wk1 = wrow[1], wk2 = wrow[2];
    uint32_t wks[3] = {wk0, wk1, wk2};
    const float* w0 = wq + ci * 576;
    #pragma unroll
    for (int ky = 0; ky < 3; ky++) {
      uint32_t bits = wks[ky] >> ox;
      float sv[3];
      sv[0] = (float)(bits & 1u);
      sv[1] = (float)((bits >> 1) & 1u);
      sv[2] = (float)((bits >> 2) & 1u);
      const float* wr = w0 + ky * 192;
      #pragma unroll
      for (int kx = 0; kx < 3; kx++) {
        const float* wp = wr + kx * 64;
        #pragma unroll
        for (int j = 0; j < 4; j++) {
          float4 wv = ((const float4*)wp)[j];
          acc[j].x = fmaf(sv[kx], wv.x, acc[j].x);
          acc[j].y = fmaf(sv[kx], wv.y, acc[j].y);
          acc[j].z = fmaf(sv[kx], wv.z, acc[j].z);
          acc[j].w = fmaf(sv[kx], wv.w, acc[j].w);
        }
      }
    }
  }
  size_t obase = ((size_t)(img0 + li) * 64 + q * 16) * 49 + p;
  #pragma unroll
  for (int j = 0; j < 4; j++) {
    out[obase + (j * 4 + 0) * 49] = acc[j].x + bias[q * 16 + j * 4 + 0];
    out[obase + (j * 4 + 1) * 49] = acc[j].y + bias[q * 16 + j * 4 + 1];
    out[obase + (j * 4 + 2) * 49] = acc[j].z + bias[q * 16 + j * 4 + 2];
    out[obase + (j * 4 + 3) * 49] = acc[j].w + bias[q * 16 + j * 4 + 3];
  }
}

// ---------------- fc1: bit spikes [1024][64ch][7row] x wT[3136,512] -> part ----
__global__ __launch_bounds__(256) void k_fc1(const uint32_t* __restrict__ s3b,
                                             const float* __restrict__ wT,
                                             float* __restrict__ part) {
  __shared__ float xs[16 * 196];
  int tid = threadIdx.x;
  int rowblk = blockIdx.x >> 4;
  int kc     = blockIdx.x & 15;
  int row0 = rowblk * 16;
  int kb   = kc * 196;
  for (int i = tid; i < 448; i += 256) {            // 16r x 4c x 7row words
    int r = i / 28, rem = i - r * 28;
    int c = rem / 7, row = rem - c * 7;
    uint32_t w = s3b[(size_t)(row0 + r) * 448 + (kc * 4 + c) * 7 + row];
    int base = r * 196 + c * 49 + row * 7;
    #pragma unroll
    for (int xq = 0; xq < 7; xq++)
      xs[base + xq] = (float)((w >> xq) & 1u);
  }
  __syncthreads();
  int oc2 = tid * 2;
  float2 acc[16];
  #pragma unroll
  for (int r = 0; r < 16; r++) { acc[r].x = 0.f; acc[r].y = 0.f; }
  const float* wp = wT + (size_t)kb * 512 + oc2;
  const float4* xs4 = (const float4*)xs;
  for (int k4 = 0; k4 < 49; k4++) {
    float2 w0 = *(const float2*)(wp + (size_t)(k4 * 4 + 0) * 512);
    float2 w1 = *(const float2*)(wp + (size_t)(k4 * 4 + 1) * 512);
    float2 w2 = *(const float2*)(wp + (size_t)(k4 * 4 + 2) * 512);
    float2 w3 = *(const float2*)(wp + (size_t)(k4 * 4 + 3) * 512);
    #pragma unroll
    for (int r = 0; r < 16; r++) {
      float4 xv = xs4[r * 49 + k4];
      acc[r].x = fmaf(xv.x, w0.x, acc[r].x);  acc[r].y = fmaf(xv.x, w0.y, acc[r].y);
      acc[r].x = fmaf(xv.y, w1.x, acc[r].x);  acc[r].y = fmaf(xv.y, w1.y, acc[r].y);
      acc[r].x = fmaf(xv.z, w2.x, acc[r].x);  acc[r].y = fmaf(xv.z, w2.y, acc[r].y);
      acc[r].x = fmaf(xv.w, w3.x, acc[r].x);  acc[r].y = fmaf(xv.w, w3.y, acc[r].y);
    }
  }
  #pragma unroll
  for (int r = 0; r < 16; r++) {
    float* o = part + (size_t)kc * 524288 + (size_t)(row0 + r) * 512 + oc2;
    o[0] = acc[r].x; o[1] = acc[r].y;
  }
}

// ---------------- fused: 16-way partial reduce + bias + LIF -> hid u8 ----------
__global__ void k_fc1red_lif(const float* __restrict__ part, const float* __restrict__ bias,
                             unsigned char* __restrict__ hid) {
  int idx = blockIdx.x * 256 + threadIdx.x;
  float bv = bias[idx & 511];
  float v = 0.f;
  #pragma unroll
  for (int t = 0; t < TT; t++) {
    float a = part[t * 65536 + idx];
    #pragma unroll
    for (int j = 1; j < 16; j++) a += part[(size_t)j * 524288 + t * 65536 + idx];
    a += bv;
    v = v + (a - v) * 0.5f;
    unsigned char s = (v >= 1.0f);
    hid[t * 65536 + idx] = s;
    if (s) v = 0.f;
  }
}

// ---------------- fco + mean over T: [8,128,512](u8) -> [128,2] ----------------
__global__ void k_fco(const unsigned char* __restrict__ hid, const float* __restrict__ w,
                      const float* __restrict__ bias, float* __restrict__ out) {
  int b = blockIdx.x, tid = threadIdx.x;
  float a0 = 0.f, a1 = 0.f;
  for (int t = 0; t < TT; t++) {
    const unsigned char* hrow = hid + ((size_t)t * 128 + b) * 512;
    for (int o = tid; o < 512; o += 256) {
      if (hrow[o]) { a0 += w[o]; a1 += w[512 + o]; }
    }
  }
  __shared__ float l0[256], l1[256];
  l0[tid] = a0; l1[tid] = a1; __syncthreads();
  for (int k = 128; k > 0; k >>= 1) {
    if (tid < k) { l0[tid] += l0[tid + k]; l1[tid] += l1[tid + k]; }
    __syncthreads();
  }
  if (tid == 0) {
    out[b * 2 + 0] = l0[0] * 0.125f + bias[0];
    out[b * 2 + 1] = l1[0] * 0.125f + bias[1];
  }
}

extern "C" void kernel_launch(void* const* d_in, const int* in_sizes, int n_in,
                              void* d_out, int out_size, void* d_ws, size_t ws_size,
                              hipStream_t stream) {
  const float* x    = (const float*)d_in[0];
  const float* c1w  = (const float*)d_in[1];
  const float* c1b  = (const float*)d_in[2];
  const float* bn1g = (const float*)d_in[3];
  const float* bn1b = (const float*)d_in[4];
  const float* c2w  = (const float*)d_in[5];
  const float* c2b  = (const float*)d_in[6];
  const float* bn2g = (const float*)d_in[7];
  const float* bn2b = (const float*)d_in[8];
  const float* c3w  = (const float*)d_in[9];
  const float* c3b  = (const float*)d_in[10];
  const float* bn3g = (const float*)d_in[11];
  const float* bn3b = (const float*)d_in[12];
  const float* fc1w = (const float*)d_in[13];
  const float* fc1b = (const float*)d_in[14];
  const float* fcow = (const float*)d_in[15];
  const float* fcob = (const float*)d_in[16];
  float* out = (float*)d_out;

  char* ws = (char*)d_ws;
  // workspace (64.9 MB footprint)
  float*    h1     = (float*)(ws + 0);                 //  6,553,600 (dead after lif1b)
  uint32_t* s1bits = (uint32_t*)(ws + 6553600);        //  2,621,440 (dead after conv2m)
  float*    h2     = (float*)(ws + 19660800);          // 21,233,664 (dead after lif2b)
  uint32_t* s2bits = (uint32_t*)(ws + 40894464);       //  2,359,296 (dead after conv3b)
  float*    h3     = (float*)(ws + 46202880);          // 12,845,056 (dead after lif3b)
  uint32_t* s3bits = (uint32_t*)(ws + 59047936);       //  1,835,008
  unsigned char* hid = (unsigned char*)(ws + 64356352);//    524,288
  float*    st     = (float*)(ws + 64880640);          //      1,280
  // persistent small weights
  __bf16* w2f   = (__bf16*)(ws + 60882944); // 196,608 (gap after s3bits)
  float* wT1    = (float*)(ws + 62390272);  // 32,768
  float* wT3    = (float*)(ws + 62423040);  // 147,456
  // overlays (lifetimes disjoint):
  float* wTf    = (float*)(ws + 0);         // 6,422,528 in h1 region (after lif1b)
  float* bnpart = (float*)(ws + 9437184);   // 8,192    in s1 region, past s1bits end
  float* f1part = (float*)(ws + 19660800);  // 33,554,432 spans dead h2+s2+h3 (fc1 time)

  prep_wT13  <<<176, 256, 0, stream>>>(c1w, c3w, wT1, wT3);
  prep_w2frag<<<384, 256, 0, stream>>>(c2w, w2f);
  k_conv1    <<<256, 256, 0, stream>>>(x, wT1, c1b, h1);
  k_bnpartial<400><<<dim3(32, 16), 256, 0, stream>>>(h1, 32, 8, bnpart);
  k_bnfinal  <<<32, 64, 0, stream>>>(bnpart, 16, 128.f * 400.f, st, st + 32);
  k_lif1b    <<<320, 256, 0, stream>>>(h1, st, st + 32, bn1g, bn1b, s1bits);
  prep_wTf   <<<dim3(98, 16), 256, 0, stream>>>(fc1w, wTf); // h1 region now free

  k_conv2m   <<<512, 256, 0, stream>>>(s1bits, w2f, c2b, h2);
  k_bnpartial<81><<<dim3(64, 16), 256, 0, stream>>>(h2, 64, 64, bnpart);
  k_bnfinal  <<<64, 64, 0, stream>>>(bnpart, 16, 1024.f * 81.f, st + 64, st + 128);
  k_lifb<9, 9><<<288, 256, 0, stream>>>(h2, st + 64, st + 128, bn2g, bn2b, s2bits, E2_ELEMS);

  k_conv3b   <<<dim3(205, 4), 256, 0, stream>>>(s2bits, wT3, c3b, h3);
  k_bnpartial<49><<<dim3(64, 16), 256, 0, stream>>>(h3, 64, 64, bnpart);
  k_bnfinal  <<<64, 64, 0, stream>>>(bnpart, 16, 1024.f * 49.f, st + 192, st + 256);
  k_lifb<7, 7><<<224, 256, 0, stream>>>(h3, st + 192, st + 256, bn3g, bn3b, s3bits, E3_ELEMS);

  k_fc1      <<<1024, 256, 0, stream>>>(s3bits, wTf, f1part); // h2/s2/h3 now free
  k_fc1red_lif<<<256, 256, 0, stream>>>(f1part, fc1b, hid);
  k_fco      <<<128, 256, 0, stream>>>(hid, fcow, fcob, out);
}

// Round 9
// 310.885 us; speedup vs baseline: 1.2697x; 1.1159x over previous
//
#include <hip/hip_runtime.h>
#include <cstdint>
#include <cstddef>

#define TT 8

#define H1_ELEMS (128*32*20*20)   // 1,638,400
#define E2_ELEMS (128*64*81)      // 663,552
#define E3_ELEMS (128*64*49)      // 401,408

typedef __attribute__((ext_vector_type(8))) short short8;
typedef __attribute__((ext_vector_type(4))) float f32x4;

// ---------------- conv1 weight transpose ----------------
__global__ void prep_wT1(const float* __restrict__ w1, float* __restrict__ wT1) {
  int i = blockIdx.x * 256 + threadIdx.x;           // 32 oc x 256 pos
  if (i >= 8192) return;
  int oc = i >> 8, pos = i & 255;
  wT1[pos * 32 + oc] = w1[oc * 256 + pos];
}

// ---------------- conv2 MFMA weight prep: fp32 -> exact 3x bf16 frag layout ----
// layout elem idx = (((term*16 + kstep)*4 + quad)*64 + oc)*8 + j ; k = kstep*32+quad*8+j
__global__ void prep_w2frag(const float* __restrict__ w2, __bf16* __restrict__ wf) {
  int i = blockIdx.x * 256 + threadIdx.x;
  if (i >= 98304) return;
  int j    = i & 7;
  int oc   = (i >> 3) & 63;
  int quad = (i >> 9) & 3;
  int ksg  = (i >> 11) & 15;
  int term = i >> 15;
  int k = ksg * 32 + quad * 8 + j;
  int ci = k >> 4, kpos = k & 15;
  float w = w2[oc * 512 + ci * 16 + kpos];
  float hf = (float)(__bf16)w;                      // exact 3-term split
  float r1 = w - hf;
  float mf = (float)(__bf16)r1;
  float r2 = r1 - mf;
  __bf16 val = (term == 0) ? (__bf16)w : (term == 1) ? (__bf16)r1 : (__bf16)r2;
  wf[i] = val;
}

// ---------------- conv3 MFMA weight prep: pos-major K = pos*64 + ci (K=576) ----
// layout elem idx = (((term*18 + kstep)*4 + quad)*64 + oc)*8 + j ; k = kstep*32+quad*8+j
__global__ void prep_w3frag(const float* __restrict__ w3, __bf16* __restrict__ wf) {
  int i = blockIdx.x * 256 + threadIdx.x;
  if (i >= 110592) return;
  int j    = i & 7;
  int oc   = (i >> 3) & 63;
  int quad = (i >> 9) & 3;
  int tk   = i >> 11;                               // term*18 + kstep
  int term = tk / 18, kstep = tk % 18;
  int k = kstep * 32 + quad * 8 + j;
  int pos = k >> 6, ci = k & 63;                    // k = pos*64 + ci
  float w = w3[oc * 576 + ci * 9 + pos];
  float hf = (float)(__bf16)w;
  float r1 = w - hf;
  float mf = (float)(__bf16)r1;
  float r2 = r1 - mf;
  __bf16 val = (term == 0) ? (__bf16)w : (term == 1) ? (__bf16)r1 : (__bf16)r2;
  wf[i] = val;
}

// tiled transpose: w[512][3136] -> wT[3136][512]
__global__ void prep_wTf(const float* __restrict__ w, float* __restrict__ wT) {
  __shared__ float tile[32][33];
  int k0 = blockIdx.x * 32;
  int o0 = blockIdx.y * 32;
  int tx = threadIdx.x & 31, ty = threadIdx.x >> 5;
  #pragma unroll
  for (int j = 0; j < 4; j++)
    tile[ty + j * 8][tx] = w[(size_t)(o0 + ty + j * 8) * 3136 + k0 + tx];
  __syncthreads();
  #pragma unroll
  for (int j = 0; j < 4; j++)
    wT[(size_t)(k0 + ty + j * 8) * 512 + o0 + tx] = tile[tx][ty + j * 8];
}

// ---------------- conv1: [128,4,84,84] -> [128,32,20,20], k8 s4 ----------------
__global__ __launch_bounds__(256) void k_conv1(const float* __restrict__ x,
                                               const float* __restrict__ wT,
                                               const float* __restrict__ bias,
                                               float* __restrict__ out) {
  __shared__ float xt[14784];                       // 59,136 B
  int tid = threadIdx.x;
  int img  = blockIdx.x >> 1;
  int half = blockIdx.x & 1;
  float4* dst = (float4*)xt;
  #pragma unroll
  for (int ci = 0; ci < 4; ci++) {
    const float4* s4 = (const float4*)(x + (size_t)img * 28224 + ci * 7056 + half * 3360);
    for (int i = tid; i < 924; i += 256) dst[ci * 924 + i] = s4[i];
  }
  __syncthreads();
  if (tid >= 200) return;
  int oyl = tid / 20, ox = tid % 20;
  float acc[32];
  #pragma unroll
  for (int j = 0; j < 32; j++) acc[j] = 0.f;
  int xb0 = oyl * 336 + ox * 4;
  #pragma unroll 1
  for (int ci = 0; ci < 4; ci++) {
    #pragma unroll 1
    for (int ky = 0; ky < 8; ky++) {
      const float* xr = xt + ci * 3696 + xb0 + ky * 84;
      float4 xa  = *(const float4*)xr;
      float4 xbv = *(const float4*)(xr + 4);
      const float* wr = wT + (ci * 8 + ky) * 256;   // wave-uniform -> s_load
      float xs[8] = {xa.x, xa.y, xa.z, xa.w, xbv.x, xbv.y, xbv.z, xbv.w};
      #pragma unroll
      for (int kx = 0; kx < 8; kx++) {
        #pragma unroll
        for (int j = 0; j < 32; j++)
          acc[j] = fmaf(xs[kx], wr[kx * 32 + j], acc[j]);
      }
    }
  }
  size_t obase = (size_t)img * 12800 + (half * 10 + oyl) * 20 + ox;
  #pragma unroll
  for (int j = 0; j < 32; j++) out[obase + j * 400] = acc[j] + bias[j];
}

// ---------------- BN stats, two-stage ----------------
template <int HW>
__global__ void k_bnpartial(const float* __restrict__ xp, int C, int Nper,
                            float* __restrict__ pout) {
  int c = blockIdx.x, s = blockIdx.y, S = gridDim.y, tid = threadIdx.x;
  int n = Nper * HW;
  float sum = 0.f, sum2 = 0.f;
  for (int i = tid; i < n; i += 256) {
    int nb = s * Nper + i / HW;
    int p  = i % HW;
    float v = xp[((size_t)nb * C + c) * HW + p];
    sum += v; sum2 += v * v;
  }
  __shared__ float l0[256], l1[256];
  l0[tid] = sum; l1[tid] = sum2; __syncthreads();
  for (int k = 128; k > 0; k >>= 1) {
    if (tid < k) { l0[tid] += l0[tid + k]; l1[tid] += l1[tid + k]; }
    __syncthreads();
  }
  if (tid == 0) { pout[(c * S + s) * 2] = l0[0]; pout[(c * S + s) * 2 + 1] = l1[0]; }
}

__global__ void k_bnfinal(const float* __restrict__ pin, int S, float n,
                          float* __restrict__ meanArr, float* __restrict__ rstdArr) {
  int c = blockIdx.x, lane = threadIdx.x;
  float s = 0.f, s2 = 0.f;
  if (lane < S) { s = pin[(c * S + lane) * 2]; s2 = pin[(c * S + lane) * 2 + 1]; }
  for (int off = 8; off > 0; off >>= 1) { s += __shfl_down(s, off); s2 += __shfl_down(s2, off); }
  if (lane == 0) {
    float m = s / n;
    float var = s2 / n - m * m;
    meanArr[c] = m;
    rstdArr[c] = rsqrtf(var + 1e-5f);
  }
}

// ---------------- BN + LIF stage 1 -> bit-packed spikes ----------------
__global__ void k_lif1b(const float* __restrict__ h, const float* __restrict__ mean,
                        const float* __restrict__ rstd, const float* __restrict__ g,
                        const float* __restrict__ bb, uint32_t* __restrict__ sout) {
  int idx = blockIdx.x * 256 + threadIdx.x;         // < 81920 = (img*32+ci)*20+row
  int ic = idx / 20;
  int ci = ic & 31;
  const float* hp = h + (size_t)idx * 20;
  float gm = g[ci], mm = mean[ci], rs = rstd[ci], bc = bb[ci];
  float xv[20];
  #pragma unroll
  for (int j4 = 0; j4 < 5; j4++) {
    float4 hv = ((const float4*)hp)[j4];
    xv[j4 * 4 + 0] = gm * (hv.x - mm) * rs + bc;
    xv[j4 * 4 + 1] = gm * (hv.y - mm) * rs + bc;
    xv[j4 * 4 + 2] = gm * (hv.z - mm) * rs + bc;
    xv[j4 * 4 + 3] = gm * (hv.w - mm) * rs + bc;
  }
  float v[20];
  #pragma unroll
  for (int j = 0; j < 20; j++) v[j] = 0.f;
  #pragma unroll
  for (int t = 0; t < TT; t++) {
    uint32_t w = 0;
    #pragma unroll
    for (int j = 0; j < 20; j++) {
      v[j] = v[j] + (xv[j] - v[j]) * 0.5f;
      uint32_t s = (v[j] >= 1.0f);
      w |= s << j;
      if (s) v[j] = 0.f;
    }
    sout[t * 81920 + idx] = w;
  }
}

// ---------------- BN + LIF generic -> bit-packed (x differs per t) ----------------
template <int W, int NROW>
__global__ void k_lifb(const float* __restrict__ h, const float* __restrict__ mean,
                       const float* __restrict__ rstd, const float* __restrict__ g,
                       const float* __restrict__ bb, uint32_t* __restrict__ sout,
                       int E) {
  int idx = blockIdx.x * 256 + threadIdx.x;
  int bc = idx / NROW;
  int c = bc & 63;
  float gm = g[c], mm = mean[c], rs = rstd[c], bcn = bb[c];
  float v[W];
  #pragma unroll
  for (int j = 0; j < W; j++) v[j] = 0.f;
  int nword = 128 * 64 * NROW;
  #pragma unroll
  for (int t = 0; t < TT; t++) {
    const float* hp = h + (size_t)t * E + (size_t)idx * W;
    uint32_t w = 0;
    #pragma unroll
    for (int j = 0; j < W; j++) {
      float xv = gm * (hp[j] - mm) * rs + bcn;
      v[j] = v[j] + (xv - v[j]) * 0.5f;
      uint32_t s = (v[j] >= 1.0f);
      w |= s << j;
      if (s) v[j] = 0.f;
    }
    sout[t * nword + idx] = w;
  }
}

// ---------------- conv2 via MFMA: C[96px][64oc] = S[96][512] x W[512][64] per img ----
__global__ __launch_bounds__(256) void k_conv2m(const uint32_t* __restrict__ s1b,
                                                const __bf16* __restrict__ wf,
                                                const float* __restrict__ bias,
                                                float* __restrict__ out) {
  __shared__ uint32_t sp[1280];                     // 2 img x 640 spike words
  __shared__ uint4 wl4[3072];                       // 49,152 B weight chunk
  __bf16* wl = (__bf16*)wl4;
  int tid = threadIdx.x;
  int img0 = blockIdx.x * 2;
  {
    const uint32_t* src = s1b + (size_t)img0 * 640;
    for (int i = tid; i < 1280; i += 256) sp[i] = src[i];
  }
  int wave = tid >> 6, lane = tid & 63;
  int img_local = wave >> 1;
  int tg = wave & 1;
  int l15 = lane & 15, quad = lane >> 4;
  int ci_off = quad >> 1;
  int kyp = (quad & 1) * 2;
  int spb[3], sh[3];
  #pragma unroll
  for (int mt = 0; mt < 3; mt++) {
    int px = tg * 48 + mt * 16 + l15;
    if (px > 80) px = 80;
    int oy = px / 9, ox = px - oy * 9;
    sh[mt]  = ox * 2;
    spb[mt] = img_local * 640 + ci_off * 20 + oy * 2 + kyp;
  }
  f32x4 acc[3][4];
  #pragma unroll
  for (int mt = 0; mt < 3; mt++)
    #pragma unroll
    for (int nt = 0; nt < 4; nt++) acc[mt][nt] = (f32x4){0.f, 0.f, 0.f, 0.f};

  for (int kc = 0; kc < 4; kc++) {
    __syncthreads();
    for (int o = tid * 8; o < 24576; o += 2048) {
      int tk = o >> 11;
      int term = tk >> 2, ksl = tk & 3;
      const __bf16* src = wf + (((term * 16 + kc * 4 + ksl)) << 11) + (o & 2047);
      *(uint4*)(wl + o) = *(const uint4*)src;
    }
    __syncthreads();
    #pragma unroll
    for (int ks = 0; ks < 4; ks++) {
      int ksg = kc * 4 + ks;
      short8 a[3];
      #pragma unroll
      for (int mt = 0; mt < 3; mt++) {
        uint32_t w0 = sp[spb[mt] + ksg * 40];
        uint32_t w1 = sp[spb[mt] + ksg * 40 + 1];
        uint32_t n0 = (w0 >> sh[mt]) & 15u;
        uint32_t n1 = (w1 >> sh[mt]) & 15u;
        union { uint32_t u[4]; short8 v; } A;
        A.u[0] = ((n0 & 1u) ? 0x3F80u : 0u) | ((n0 & 2u) ? 0x3F800000u : 0u);
        A.u[1] = ((n0 & 4u) ? 0x3F80u : 0u) | ((n0 & 8u) ? 0x3F800000u : 0u);
        A.u[2] = ((n1 & 1u) ? 0x3F80u : 0u) | ((n1 & 2u) ? 0x3F800000u : 0u);
        A.u[3] = ((n1 & 4u) ? 0x3F80u : 0u) | ((n1 & 8u) ? 0x3F800000u : 0u);
        a[mt] = A.v;
      }
      #pragma unroll
      for (int term = 0; term < 3; term++) {
        int fb = ((term * 4 + ks) << 11) + (quad << 9);
        #pragma unroll
        for (int nt = 0; nt < 4; nt++) {
          short8 b = *(const short8*)(wl + fb + ((nt << 4) + l15) * 8);
          #pragma unroll
          for (int mt = 0; mt < 3; mt++)
            acc[mt][nt] = __builtin_amdgcn_mfma_f32_16x16x32_bf16(a[mt], b, acc[mt][nt], 0, 0, 0);
        }
      }
    }
  }
  #pragma unroll
  for (int nt = 0; nt < 4; nt++) {
    int oc = nt * 16 + l15;
    float bv = bias[oc];
    float* op = out + ((size_t)(img0 + img_local) * 64 + oc) * 81;
    #pragma unroll
    for (int mt = 0; mt < 3; mt++) {
      int pxr = tg * 48 + mt * 16 + quad * 4;
      #pragma unroll
      for (int r = 0; r < 4; r++) {
        int px = pxr + r;
        if (px < 81) op[px] = acc[mt][nt][r] + bv;
      }
    }
  }
}

// ---------------- spike repack for conv3: [n][64ch][9row](bit=col) -> [n][9r][9c][2half](bit=ci) ----
__global__ void k_s2T(const uint32_t* __restrict__ sbits, uint32_t* __restrict__ s2T) {
  __shared__ uint32_t sb[576];
  int n = blockIdx.x;
  int t = n >> 7, b = n & 127;
  int tid = threadIdx.x;
  const uint32_t* src = sbits + t * 73728 + b * 576;
  for (int i = tid; i < 576; i += 256) sb[i] = src[i];
  __syncthreads();
  if (tid >= 162) return;
  int half = tid & 1, pc = tid >> 1;                // pc = r*9 + col
  int r = pc / 9, cpix = pc - r * 9;
  uint32_t w = 0;
  #pragma unroll
  for (int ci = 0; ci < 32; ci++)
    w |= (((sb[(half * 32 + ci) * 9 + r] >> cpix) & 1u) << ci);
  s2T[(size_t)n * 162 + pc * 2 + half] = w;
}

// ---------------- conv3 via MFMA: C[49px][64oc] = S[49][576] x W[576][64] per img ----
// K pos-major: k = pos*64 + ci, 18 ksteps, zero padding. Block = 2 imgs, 4 waves.
__global__ __launch_bounds__(256) void k_conv3m(const uint32_t* __restrict__ s2T,
                                                const __bf16* __restrict__ wf,
                                                const float* __restrict__ bias,
                                                float* __restrict__ out) {
  __shared__ uint32_t sp[324];                      // 2 img x 162 words
  __shared__ uint4 wl4[4608];                       // 73,728 B weight chunk
  __bf16* wl = (__bf16*)wl4;
  int tid = threadIdx.x;
  int img0 = blockIdx.x * 2;
  {
    const uint32_t* src = s2T + (size_t)img0 * 162;
    for (int i = tid; i < 324; i += 256) sp[i] = src[i];
  }
  int wave = tid >> 6, lane = tid & 63;
  int img_local = wave >> 1, tg = wave & 1;
  int l15 = lane & 15, quad = lane >> 4;
  int qsh = quad * 8;
  int base[2];
  #pragma unroll
  for (int mt = 0; mt < 2; mt++) {
    int px = tg * 32 + mt * 16 + l15;
    if (px > 48) px = 48;                           // pad lanes clamped; stores masked
    int oy = px / 7, ox = px - oy * 7;
    base[mt] = img_local * 162 + (oy * 9 + ox) * 2;
  }
  f32x4 acc[2][4];
  #pragma unroll
  for (int mt = 0; mt < 2; mt++)
    #pragma unroll
    for (int nt = 0; nt < 4; nt++) acc[mt][nt] = (f32x4){0.f, 0.f, 0.f, 0.f};

  #pragma unroll
  for (int kc = 0; kc < 3; kc++) {
    __syncthreads();
    #pragma unroll
    for (int it = 0; it < 18; it++) {               // stage 3 terms x 6 ksteps
      const __bf16* s = wf + (((it / 6) * 18 + kc * 6 + (it % 6)) << 11) + tid * 8;
      *(uint4*)(wl + (it << 11) + tid * 8) = *(const uint4*)s;
    }
    __syncthreads();
    #pragma unroll
    for (int ksl = 0; ksl < 6; ksl++) {
      int kstep = kc * 6 + ksl;                     // compile-time
      int pos = kstep >> 1, cihalf = kstep & 1;
      int ky = pos / 3, kx = pos % 3;
      short8 a[2];
      #pragma unroll
      for (int mt = 0; mt < 2; mt++) {
        uint32_t word = sp[base[mt] + (ky * 9 + kx) * 2 + cihalf];
        uint32_t byt = (word >> qsh) & 255u;
        union { uint32_t u[4]; short8 v; } A;
        A.u[0] = ((byt & 1u)  ? 0x3F80u : 0u) | ((byt & 2u)   ? 0x3F800000u : 0u);
        A.u[1] = ((byt & 4u)  ? 0x3F80u : 0u) | ((byt & 8u)   ? 0x3F800000u : 0u);
        A.u[2] = ((byt & 16u) ? 0x3F80u : 0u) | ((byt & 32u)  ? 0x3F800000u : 0u);
        A.u[3] = ((byt & 64u) ? 0x3F80u : 0u) | ((byt & 128u) ? 0x3F800000u : 0u);
        a[mt] = A.v;
      }
      #pragma unroll
      for (int term = 0; term < 3; term++) {
        int fb = ((term * 6 + ksl) << 11) + (quad << 9);
        #pragma unroll
        for (int nt = 0; nt < 4; nt++) {
          short8 b = *(const short8*)(wl + fb + ((nt << 4) + l15) * 8);
          #pragma unroll
          for (int mt = 0; mt < 2; mt++)
            acc[mt][nt] = __builtin_amdgcn_mfma_f32_16x16x32_bf16(a[mt], b, acc[mt][nt], 0, 0, 0);
        }
      }
    }
  }
  #pragma unroll
  for (int nt = 0; nt < 4; nt++) {
    int oc = nt * 16 + l15;
    float bv = bias[oc];
    float* op = out + ((size_t)(img0 + img_local) * 64 + oc) * 49;
    #pragma unroll
    for (int mt = 0; mt < 2; mt++) {
      int pxr = tg * 32 + mt * 16 + quad * 4;
      #pragma unroll
      for (int r = 0; r < 4; r++) {
        int px = pxr + r;
        if (px < 49) op[px] = acc[mt][nt][r] + bv;
      }
    }
  }
}

// ---------------- fc1: bit spikes [1024][64ch][7row] x wT[3136,512] -> part ----
__global__ __launch_bounds__(256) void k_fc1(const uint32_t* __restrict__ s3b,
                                             const float* __restrict__ wT,
                                             float* __restrict__ part) {
  __shared__ float xs[16 * 196];
  int tid = threadIdx.x;
  int rowblk = blockIdx.x >> 4;
  int kc     = blockIdx.x & 15;
  int row0 = rowblk * 16;
  int kb   = kc * 196;
  for (int i = tid; i < 448; i += 256) {            // 16r x 4c x 7row words
    int r = i / 28, rem = i - r * 28;
    int c = rem / 7, row = rem - c * 7;
    uint32_t w = s3b[(size_t)(row0 + r) * 448 + (kc * 4 + c) * 7 + row];
    int base = r * 196 + c * 49 + row * 7;
    #pragma unroll
    for (int xq = 0; xq < 7; xq++)
      xs[base + xq] = (float)((w >> xq) & 1u);
  }
  __syncthreads();
  int oc2 = tid * 2;
  float2 acc[16];
  #pragma unroll
  for (int r = 0; r < 16; r++) { acc[r].x = 0.f; acc[r].y = 0.f; }
  const float* wp = wT + (size_t)kb * 512 + oc2;
  const float4* xs4 = (const float4*)xs;
  for (int k4 = 0; k4 < 49; k4++) {
    float2 w0 = *(const float2*)(wp + (size_t)(k4 * 4 + 0) * 512);
    float2 w1 = *(const float2*)(wp + (size_t)(k4 * 4 + 1) * 512);
    float2 w2 = *(const float2*)(wp + (size_t)(k4 * 4 + 2) * 512);
    float2 w3 = *(const float2*)(wp + (size_t)(k4 * 4 + 3) * 512);
    #pragma unroll
    for (int r = 0; r < 16; r++) {
      float4 xv = xs4[r * 49 + k4];
      acc[r].x = fmaf(xv.x, w0.x, acc[r].x);  acc[r].y = fmaf(xv.x, w0.y, acc[r].y);
      acc[r].x = fmaf(xv.y, w1.x, acc[r].x);  acc[r].y = fmaf(xv.y, w1.y, acc[r].y);
      acc[r].x = fmaf(xv.z, w2.x, acc[r].x);  acc[r].y = fmaf(xv.z, w2.y, acc[r].y);
      acc[r].x = fmaf(xv.w, w3.x, acc[r].x);  acc[r].y = fmaf(xv.w, w3.y, acc[r].y);
    }
  }
  #pragma unroll
  for (int r = 0; r < 16; r++) {
    float* o = part + (size_t)kc * 524288 + (size_t)(row0 + r) * 512 + oc2;
    o[0] = acc[r].x; o[1] = acc[r].y;
  }
}

// ---------------- fused: 16-way partial reduce + bias + LIF -> hid u8 ----------
__global__ void k_fc1red_lif(const float* __restrict__ part, const float* __restrict__ bias,
                             unsigned char* __restrict__ hid) {
  int idx = blockIdx.x * 256 + threadIdx.x;
  float bv = bias[idx & 511];
  float v = 0.f;
  #pragma unroll
  for (int t = 0; t < TT; t++) {
    float a = part[t * 65536 + idx];
    #pragma unroll
    for (int j = 1; j < 16; j++) a += part[(size_t)j * 524288 + t * 65536 + idx];
    a += bv;
    v = v + (a - v) * 0.5f;
    unsigned char s = (v >= 1.0f);
    hid[t * 65536 + idx] = s;
    if (s) v = 0.f;
  }
}

// ---------------- fco + mean over T: [8,128,512](u8) -> [128,2] ----------------
__global__ void k_fco(const unsigned char* __restrict__ hid, const float* __restrict__ w,
                      const float* __restrict__ bias, float* __restrict__ out) {
  int b = blockIdx.x, tid = threadIdx.x;
  float a0 = 0.f, a1 = 0.f;
  for (int t = 0; t < TT; t++) {
    const unsigned char* hrow = hid + ((size_t)t * 128 + b) * 512;
    for (int o = tid; o < 512; o += 256) {
      if (hrow[o]) { a0 += w[o]; a1 += w[512 + o]; }
    }
  }
  __shared__ float l0[256], l1[256];
  l0[tid] = a0; l1[tid] = a1; __syncthreads();
  for (int k = 128; k > 0; k >>= 1) {
    if (tid < k) { l0[tid] += l0[tid + k]; l1[tid] += l1[tid + k]; }
    __syncthreads();
  }
  if (tid == 0) {
    out[b * 2 + 0] = l0[0] * 0.125f + bias[0];
    out[b * 2 + 1] = l1[0] * 0.125f + bias[1];
  }
}

extern "C" void kernel_launch(void* const* d_in, const int* in_sizes, int n_in,
                              void* d_out, int out_size, void* d_ws, size_t ws_size,
                              hipStream_t stream) {
  const float* x    = (const float*)d_in[0];
  const float* c1w  = (const float*)d_in[1];
  const float* c1b  = (const float*)d_in[2];
  const float* bn1g = (const float*)d_in[3];
  const float* bn1b = (const float*)d_in[4];
  const float* c2w  = (const float*)d_in[5];
  const float* c2b  = (const float*)d_in[6];
  const float* bn2g = (const float*)d_in[7];
  const float* bn2b = (const float*)d_in[8];
  const float* c3w  = (const float*)d_in[9];
  const float* c3b  = (const float*)d_in[10];
  const float* bn3g = (const float*)d_in[11];
  const float* bn3b = (const float*)d_in[12];
  const float* fc1w = (const float*)d_in[13];
  const float* fc1b = (const float*)d_in[14];
  const float* fcow = (const float*)d_in[15];
  const float* fcob = (const float*)d_in[16];
  float* out = (float*)d_out;

  char* ws = (char*)d_ws;
  // workspace (64.9 MB footprint)
  float*    h1     = (float*)(ws + 0);                 //  6,553,600 (dead after lif1b)
  uint32_t* s1bits = (uint32_t*)(ws + 6553600);        //  2,621,440 (dead after conv2m)
  float*    h2     = (float*)(ws + 19660800);          // 21,233,664 (dead after lif2b)
  uint32_t* s2bits = (uint32_t*)(ws + 40894464);       //  2,359,296 (dead after k_s2T)
  float*    h3     = (float*)(ws + 46202880);          // 12,845,056 (dead after lif3b)
  uint32_t* s3bits = (uint32_t*)(ws + 59047936);       //  1,835,008
  unsigned char* hid = (unsigned char*)(ws + 64356352);//    524,288
  float*    st     = (float*)(ws + 64880640);          //      1,280
  // persistent small weights (gap 60,882,944 .. 62,423,040)
  __bf16*   w2f  = (__bf16*)(ws + 60882944);  // 196,608
  __bf16*   w3f  = (__bf16*)(ws + 61079552);  // 221,184
  uint32_t* s2T  = (uint32_t*)(ws + 61300736);// 663,552 (written after lif2b)
  float*    wT1  = (float*)(ws + 62390272);   // 32,768
  // overlays (lifetimes disjoint):
  float* wTf    = (float*)(ws + 0);         // 6,422,528 in h1 region (after lif1b)
  float* bnpart = (float*)(ws + 9437184);   // 8,192    in s1 region, past s1bits end
  float* f1part = (float*)(ws + 19660800);  // 33,554,432 spans dead h2+s2+h3 (fc1 time)

  prep_wT1   <<<32, 256, 0, stream>>>(c1w, wT1);
  prep_w2frag<<<384, 256, 0, stream>>>(c2w, w2f);
  prep_w3frag<<<432, 256, 0, stream>>>(c3w, w3f);
  k_conv1    <<<256, 256, 0, stream>>>(x, wT1, c1b, h1);
  k_bnpartial<400><<<dim3(32, 16), 256, 0, stream>>>(h1, 32, 8, bnpart);
  k_bnfinal  <<<32, 64, 0, stream>>>(bnpart, 16, 128.f * 400.f, st, st + 32);
  k_lif1b    <<<320, 256, 0, stream>>>(h1, st, st + 32, bn1g, bn1b, s1bits);
  prep_wTf   <<<dim3(98, 16), 256, 0, stream>>>(fc1w, wTf); // h1 region now free

  k_conv2m   <<<512, 256, 0, stream>>>(s1bits, w2f, c2b, h2);
  k_bnpartial<81><<<dim3(64, 16), 256, 0, stream>>>(h2, 64, 64, bnpart);
  k_bnfinal  <<<64, 64, 0, stream>>>(bnpart, 16, 1024.f * 81.f, st + 64, st + 128);
  k_lifb<9, 9><<<288, 256, 0, stream>>>(h2, st + 64, st + 128, bn2g, bn2b, s2bits, E2_ELEMS);

  k_s2T      <<<1024, 256, 0, stream>>>(s2bits, s2T);
  k_conv3m   <<<512, 256, 0, stream>>>(s2T, w3f, c3b, h3);
  k_bnpartial<49><<<dim3(64, 16), 256, 0, stream>>>(h3, 64, 64, bnpart);
  k_bnfinal  <<<64, 64, 0, stream>>>(bnpart, 16, 1024.f * 49.f, st + 192, st + 256);
  k_lifb<7, 7><<<224, 256, 0, stream>>>(h3, st + 192, st + 256, bn3g, bn3b, s3bits, E3_ELEMS);

  k_fc1      <<<1024, 256, 0, stream>>>(s3bits, wTf, f1part); // h2/s2/h3 now free
  k_fc1red_lif<<<256, 256, 0, stream>>>(f1part, fc1b, hid);
  k_fco      <<<128, 256, 0, stream>>>(hid, fcow, fcob, out);
}

// Round 10
// 285.981 us; speedup vs baseline: 1.3802x; 1.0871x over previous
//
#include <hip/hip_runtime.h>
#include <cstdint>
#include <cstddef>

#define TT 8

#define H1_ELEMS (128*32*20*20)   // 1,638,400
#define E2_ELEMS (128*64*81)      // 663,552
#define E3_ELEMS (128*64*49)      // 401,408

typedef __attribute__((ext_vector_type(8))) short short8;
typedef __attribute__((ext_vector_type(4))) float f32x4;

// ---------------- conv1 weight prep: [ochalf][pos][16oc] ----------------
__global__ void prep_wT1(const float* __restrict__ w1, float* __restrict__ wT1) {
  int i = blockIdx.x * 256 + threadIdx.x;           // 32 oc x 256 pos
  if (i >= 8192) return;
  int oc = i >> 8, pos = i & 255;
  wT1[(oc >> 4) * 4096 + pos * 16 + (oc & 15)] = w1[oc * 256 + pos];
}

// ---------------- conv2 MFMA weight prep: fp32 -> exact 3x bf16 frag layout ----
// layout elem idx = (((term*16 + kstep)*4 + quad)*64 + oc)*8 + j ; k = kstep*32+quad*8+j
__global__ void prep_w2frag(const float* __restrict__ w2, __bf16* __restrict__ wf) {
  int i = blockIdx.x * 256 + threadIdx.x;
  if (i >= 98304) return;
  int j    = i & 7;
  int oc   = (i >> 3) & 63;
  int quad = (i >> 9) & 3;
  int ksg  = (i >> 11) & 15;
  int term = i >> 15;
  int k = ksg * 32 + quad * 8 + j;
  int ci = k >> 4, kpos = k & 15;
  float w = w2[oc * 512 + ci * 16 + kpos];
  float hf = (float)(__bf16)w;                      // exact 3-term split
  float r1 = w - hf;
  float mf = (float)(__bf16)r1;
  float r2 = r1 - mf;
  __bf16 val = (term == 0) ? (__bf16)w : (term == 1) ? (__bf16)r1 : (__bf16)r2;
  wf[i] = val;
}

// ---------------- conv3 MFMA weight prep: pos-major K = pos*64 + ci (K=576) ----
__global__ void prep_w3frag(const float* __restrict__ w3, __bf16* __restrict__ wf) {
  int i = blockIdx.x * 256 + threadIdx.x;
  if (i >= 110592) return;
  int j    = i & 7;
  int oc   = (i >> 3) & 63;
  int quad = (i >> 9) & 3;
  int tk   = i >> 11;                               // term*18 + kstep
  int term = tk / 18, kstep = tk % 18;
  int k = kstep * 32 + quad * 8 + j;
  int pos = k >> 6, ci = k & 63;                    // k = pos*64 + ci
  float w = w3[oc * 576 + ci * 9 + pos];
  float hf = (float)(__bf16)w;
  float r1 = w - hf;
  float mf = (float)(__bf16)r1;
  float r2 = r1 - mf;
  __bf16 val = (term == 0) ? (__bf16)w : (term == 1) ? (__bf16)r1 : (__bf16)r2;
  wf[i] = val;
}

// tiled transpose: w[512][3136] -> wT[3136][512]
__global__ void prep_wTf(const float* __restrict__ w, float* __restrict__ wT) {
  __shared__ float tile[32][33];
  int k0 = blockIdx.x * 32;
  int o0 = blockIdx.y * 32;
  int tx = threadIdx.x & 31, ty = threadIdx.x >> 5;
  #pragma unroll
  for (int j = 0; j < 4; j++)
    tile[ty + j * 8][tx] = w[(size_t)(o0 + ty + j * 8) * 3136 + k0 + tx];
  __syncthreads();
  #pragma unroll
  for (int j = 0; j < 4; j++)
    wT[(size_t)(k0 + ty + j * 8) * 512 + o0 + tx] = tile[tx][ty + j * 8];
}

// ---------------- conv1: [128,4,84,84] -> [128,32,20,20], k8 s4 ----------------
// grid (img*4+q, ochalf), 128 thr. Slab 4ch x 24rows x 84. Thread = 1 px, 16 oc acc.
__global__ __launch_bounds__(128) void k_conv1(const float* __restrict__ x,
                                               const float* __restrict__ wT,
                                               const float* __restrict__ bias,
                                               float* __restrict__ out) {
  __shared__ float xt[8064];                        // 32,256 B
  int tid = threadIdx.x;
  int img = blockIdx.x >> 2;
  int q   = blockIdx.x & 3;
  int och = blockIdx.y;
  float4* dst = (float4*)xt;
  #pragma unroll
  for (int ci = 0; ci < 4; ci++) {
    const float4* s4 = (const float4*)(x + (size_t)img * 28224 + ci * 7056 + q * 1680);
    for (int i = tid; i < 504; i += 128) dst[ci * 504 + i] = s4[i];
  }
  __syncthreads();
  if (tid >= 100) return;
  int oyl = tid / 20, ox = tid % 20;
  float acc[16];
  #pragma unroll
  for (int j = 0; j < 16; j++) acc[j] = 0.f;
  int xb0 = oyl * 336 + ox * 4;                     // (oyl*4)*84 + ox*4
  const float* wh = wT + och * 4096;
  #pragma unroll 1
  for (int ci = 0; ci < 4; ci++) {
    #pragma unroll 1
    for (int ky = 0; ky < 8; ky++) {
      const float* xr = xt + ci * 2016 + xb0 + ky * 84;
      float4 xa  = *(const float4*)xr;
      float4 xbv = *(const float4*)(xr + 4);
      const float* wr = wh + (ci * 8 + ky) * 128;   // wave-uniform -> s_load
      float xs[8] = {xa.x, xa.y, xa.z, xa.w, xbv.x, xbv.y, xbv.z, xbv.w};
      #pragma unroll
      for (int kx = 0; kx < 8; kx++) {
        #pragma unroll
        for (int j = 0; j < 16; j++)
          acc[j] = fmaf(xs[kx], wr[kx * 16 + j], acc[j]);
      }
    }
  }
  size_t obase = (size_t)img * 12800 + och * 6400 + (q * 5 + oyl) * 20 + ox;
  #pragma unroll
  for (int j = 0; j < 16; j++) out[obase + j * 400] = acc[j] + bias[och * 16 + j];
}

// ---------------- BN stats, two-stage ----------------
template <int HW>
__global__ void k_bnpartial(const float* __restrict__ xp, int C, int Nper,
                            float* __restrict__ pout) {
  int c = blockIdx.x, s = blockIdx.y, S = gridDim.y, tid = threadIdx.x;
  int n = Nper * HW;
  float sum = 0.f, sum2 = 0.f;
  for (int i = tid; i < n; i += 256) {
    int nb = s * Nper + i / HW;
    int p  = i % HW;
    float v = xp[((size_t)nb * C + c) * HW + p];
    sum += v; sum2 += v * v;
  }
  __shared__ float l0[256], l1[256];
  l0[tid] = sum; l1[tid] = sum2; __syncthreads();
  for (int k = 128; k > 0; k >>= 1) {
    if (tid < k) { l0[tid] += l0[tid + k]; l1[tid] += l1[tid + k]; }
    __syncthreads();
  }
  if (tid == 0) { pout[(c * S + s) * 2] = l0[0]; pout[(c * S + s) * 2 + 1] = l1[0]; }
}

__global__ void k_bnfinal(const float* __restrict__ pin, int S, float n,
                          float* __restrict__ meanArr, float* __restrict__ rstdArr) {
  int c = blockIdx.x, lane = threadIdx.x;
  float s = 0.f, s2 = 0.f;
  if (lane < S) { s = pin[(c * S + lane) * 2]; s2 = pin[(c * S + lane) * 2 + 1]; }
  for (int off = 8; off > 0; off >>= 1) { s += __shfl_down(s, off); s2 += __shfl_down(s2, off); }
  if (lane == 0) {
    float m = s / n;
    float var = s2 / n - m * m;
    meanArr[c] = m;
    rstdArr[c] = rsqrtf(var + 1e-5f);
  }
}

// ---------------- BN + LIF stage 1 -> bit-packed spikes ----------------
__global__ void k_lif1b(const float* __restrict__ h, const float* __restrict__ mean,
                        const float* __restrict__ rstd, const float* __restrict__ g,
                        const float* __restrict__ bb, uint32_t* __restrict__ sout) {
  int idx = blockIdx.x * 256 + threadIdx.x;         // < 81920 = (img*32+ci)*20+row
  int ic = idx / 20;
  int ci = ic & 31;
  const float* hp = h + (size_t)idx * 20;
  float gm = g[ci], mm = mean[ci], rs = rstd[ci], bc = bb[ci];
  float xv[20];
  #pragma unroll
  for (int j4 = 0; j4 < 5; j4++) {
    float4 hv = ((const float4*)hp)[j4];
    xv[j4 * 4 + 0] = gm * (hv.x - mm) * rs + bc;
    xv[j4 * 4 + 1] = gm * (hv.y - mm) * rs + bc;
    xv[j4 * 4 + 2] = gm * (hv.z - mm) * rs + bc;
    xv[j4 * 4 + 3] = gm * (hv.w - mm) * rs + bc;
  }
  float v[20];
  #pragma unroll
  for (int j = 0; j < 20; j++) v[j] = 0.f;
  #pragma unroll
  for (int t = 0; t < TT; t++) {
    uint32_t w = 0;
    #pragma unroll
    for (int j = 0; j < 20; j++) {
      v[j] = v[j] + (xv[j] - v[j]) * 0.5f;
      uint32_t s = (v[j] >= 1.0f);
      w |= s << j;
      if (s) v[j] = 0.f;
    }
    sout[t * 81920 + idx] = w;
  }
}

// ---------------- BN + LIF generic -> bit-packed (x differs per t) ----------------
template <int W, int NROW>
__global__ void k_lifb(const float* __restrict__ h, const float* __restrict__ mean,
                       const float* __restrict__ rstd, const float* __restrict__ g,
                       const float* __restrict__ bb, uint32_t* __restrict__ sout,
                       int E) {
  int idx = blockIdx.x * 256 + threadIdx.x;
  int bc = idx / NROW;
  int c = bc & 63;
  float gm = g[c], mm = mean[c], rs = rstd[c], bcn = bb[c];
  float v[W];
  #pragma unroll
  for (int j = 0; j < W; j++) v[j] = 0.f;
  int nword = 128 * 64 * NROW;
  #pragma unroll
  for (int t = 0; t < TT; t++) {
    const float* hp = h + (size_t)t * E + (size_t)idx * W;
    uint32_t w = 0;
    #pragma unroll
    for (int j = 0; j < W; j++) {
      float xv = gm * (hp[j] - mm) * rs + bcn;
      v[j] = v[j] + (xv - v[j]) * 0.5f;
      uint32_t s = (v[j] >= 1.0f);
      w |= s << j;
      if (s) v[j] = 0.f;
    }
    sout[t * nword + idx] = w;
  }
}

// ---------------- conv2 via MFMA: C[96px][64oc] = S[96][512] x W[512][64] per img ----
__global__ __launch_bounds__(256) void k_conv2m(const uint32_t* __restrict__ s1b,
                                                const __bf16* __restrict__ wf,
                                                const float* __restrict__ bias,
                                                float* __restrict__ out) {
  __shared__ uint32_t sp[1280];                     // 2 img x 640 spike words
  __shared__ uint4 wl4[3072];                       // 49,152 B weight chunk
  __bf16* wl = (__bf16*)wl4;
  int tid = threadIdx.x;
  int img0 = blockIdx.x * 2;
  {
    const uint32_t* src = s1b + (size_t)img0 * 640;
    for (int i = tid; i < 1280; i += 256) sp[i] = src[i];
  }
  int wave = tid >> 6, lane = tid & 63;
  int img_local = wave >> 1;
  int tg = wave & 1;
  int l15 = lane & 15, quad = lane >> 4;
  int ci_off = quad >> 1;
  int kyp = (quad & 1) * 2;
  int spb[3], sh[3];
  #pragma unroll
  for (int mt = 0; mt < 3; mt++) {
    int px = tg * 48 + mt * 16 + l15;
    if (px > 80) px = 80;
    int oy = px / 9, ox = px - oy * 9;
    sh[mt]  = ox * 2;
    spb[mt] = img_local * 640 + ci_off * 20 + oy * 2 + kyp;
  }
  f32x4 acc[3][4];
  #pragma unroll
  for (int mt = 0; mt < 3; mt++)
    #pragma unroll
    for (int nt = 0; nt < 4; nt++) acc[mt][nt] = (f32x4){0.f, 0.f, 0.f, 0.f};

  for (int kc = 0; kc < 4; kc++) {
    __syncthreads();
    for (int o = tid * 8; o < 24576; o += 2048) {
      int tk = o >> 11;
      int term = tk >> 2, ksl = tk & 3;
      const __bf16* src = wf + (((term * 16 + kc * 4 + ksl)) << 11) + (o & 2047);
      *(uint4*)(wl + o) = *(const uint4*)src;
    }
    __syncthreads();
    #pragma unroll
    for (int ks = 0; ks < 4; ks++) {
      int ksg = kc * 4 + ks;
      short8 a[3];
      #pragma unroll
      for (int mt = 0; mt < 3; mt++) {
        uint32_t w0 = sp[spb[mt] + ksg * 40];
        uint32_t w1 = sp[spb[mt] + ksg * 40 + 1];
        uint32_t n0 = (w0 >> sh[mt]) & 15u;
        uint32_t n1 = (w1 >> sh[mt]) & 15u;
        union { uint32_t u[4]; short8 v; } A;
        A.u[0] = ((n0 & 1u) ? 0x3F80u : 0u) | ((n0 & 2u) ? 0x3F800000u : 0u);
        A.u[1] = ((n0 & 4u) ? 0x3F80u : 0u) | ((n0 & 8u) ? 0x3F800000u : 0u);
        A.u[2] = ((n1 & 1u) ? 0x3F80u : 0u) | ((n1 & 2u) ? 0x3F800000u : 0u);
        A.u[3] = ((n1 & 4u) ? 0x3F80u : 0u) | ((n1 & 8u) ? 0x3F800000u : 0u);
        a[mt] = A.v;
      }
      #pragma unroll
      for (int term = 0; term < 3; term++) {
        int fb = ((term * 4 + ks) << 11) + (quad << 9);
        #pragma unroll
        for (int nt = 0; nt < 4; nt++) {
          short8 b = *(const short8*)(wl + fb + ((nt << 4) + l15) * 8);
          #pragma unroll
          for (int mt = 0; mt < 3; mt++)
            acc[mt][nt] = __builtin_amdgcn_mfma_f32_16x16x32_bf16(a[mt], b, acc[mt][nt], 0, 0, 0);
        }
      }
    }
  }
  #pragma unroll
  for (int nt = 0; nt < 4; nt++) {
    int oc = nt * 16 + l15;
    float bv = bias[oc];
    float* op = out + ((size_t)(img0 + img_local) * 64 + oc) * 81;
    #pragma unroll
    for (int mt = 0; mt < 3; mt++) {
      int pxr = tg * 48 + mt * 16 + quad * 4;
      #pragma unroll
      for (int r = 0; r < 4; r++) {
        int px = pxr + r;
        if (px < 81) op[px] = acc[mt][nt][r] + bv;
      }
    }
  }
}

// ---------------- spike repack for conv3: [n][64ch][9row](bit=col) -> [n][9r][9c][2half](bit=ci) ----
__global__ void k_s2T(const uint32_t* __restrict__ sbits, uint32_t* __restrict__ s2T) {
  __shared__ uint32_t sb[576];
  int n = blockIdx.x;
  int t = n >> 7, b = n & 127;
  int tid = threadIdx.x;
  const uint32_t* src = sbits + t * 73728 + b * 576;
  for (int i = tid; i < 576; i += 256) sb[i] = src[i];
  __syncthreads();
  if (tid >= 162) return;
  int half = tid & 1, pc = tid >> 1;                // pc = r*9 + col
  int r = pc / 9, cpix = pc - r * 9;
  uint32_t w = 0;
  #pragma unroll
  for (int ci = 0; ci < 32; ci++)
    w |= (((sb[(half * 32 + ci) * 9 + r] >> cpix) & 1u) << ci);
  s2T[(size_t)n * 162 + pc * 2 + half] = w;
}

// ---------------- conv3 via MFMA: C[49px][64oc] = S[49][576] x W[576][64] per img ----
__global__ __launch_bounds__(256) void k_conv3m(const uint32_t* __restrict__ s2T,
                                                const __bf16* __restrict__ wf,
                                                const float* __restrict__ bias,
                                                float* __restrict__ out) {
  __shared__ uint32_t sp[324];                      // 2 img x 162 words
  __shared__ uint4 wl4[4608];                       // 73,728 B weight chunk
  __bf16* wl = (__bf16*)wl4;
  int tid = threadIdx.x;
  int img0 = blockIdx.x * 2;
  {
    const uint32_t* src = s2T + (size_t)img0 * 162;
    for (int i = tid; i < 324; i += 256) sp[i] = src[i];
  }
  int wave = tid >> 6, lane = tid & 63;
  int img_local = wave >> 1, tg = wave & 1;
  int l15 = lane & 15, quad = lane >> 4;
  int qsh = quad * 8;
  int base[2];
  #pragma unroll
  for (int mt = 0; mt < 2; mt++) {
    int px = tg * 32 + mt * 16 + l15;
    if (px > 48) px = 48;
    int oy = px / 7, ox = px - oy * 7;
    base[mt] = img_local * 162 + (oy * 9 + ox) * 2;
  }
  f32x4 acc[2][4];
  #pragma unroll
  for (int mt = 0; mt < 2; mt++)
    #pragma unroll
    for (int nt = 0; nt < 4; nt++) acc[mt][nt] = (f32x4){0.f, 0.f, 0.f, 0.f};

  #pragma unroll
  for (int kc = 0; kc < 3; kc++) {
    __syncthreads();
    #pragma unroll
    for (int it = 0; it < 18; it++) {
      const __bf16* s = wf + (((it / 6) * 18 + kc * 6 + (it % 6)) << 11) + tid * 8;
      *(uint4*)(wl + (it << 11) + tid * 8) = *(const uint4*)s;
    }
    __syncthreads();
    #pragma unroll
    for (int ksl = 0; ksl < 6; ksl++) {
      int kstep = kc * 6 + ksl;
      int pos = kstep >> 1, cihalf = kstep & 1;
      int ky = pos / 3, kx = pos % 3;
      short8 a[2];
      #pragma unroll
      for (int mt = 0; mt < 2; mt++) {
        uint32_t word = sp[base[mt] + (ky * 9 + kx) * 2 + cihalf];
        uint32_t byt = (word >> qsh) & 255u;
        union { uint32_t u[4]; short8 v; } A;
        A.u[0] = ((byt & 1u)  ? 0x3F80u : 0u) | ((byt & 2u)   ? 0x3F800000u : 0u);
        A.u[1] = ((byt & 4u)  ? 0x3F80u : 0u) | ((byt & 8u)   ? 0x3F800000u : 0u);
        A.u[2] = ((byt & 16u) ? 0x3F80u : 0u) | ((byt & 32u)  ? 0x3F800000u : 0u);
        A.u[3] = ((byt & 64u) ? 0x3F80u : 0u) | ((byt & 128u) ? 0x3F800000u : 0u);
        a[mt] = A.v;
      }
      #pragma unroll
      for (int term = 0; term < 3; term++) {
        int fb = ((term * 6 + ksl) << 11) + (quad << 9);
        #pragma unroll
        for (int nt = 0; nt < 4; nt++) {
          short8 b = *(const short8*)(wl + fb + ((nt << 4) + l15) * 8);
          #pragma unroll
          for (int mt = 0; mt < 2; mt++)
            acc[mt][nt] = __builtin_amdgcn_mfma_f32_16x16x32_bf16(a[mt], b, acc[mt][nt], 0, 0, 0);
        }
      }
    }
  }
  #pragma unroll
  for (int nt = 0; nt < 4; nt++) {
    int oc = nt * 16 + l15;
    float bv = bias[oc];
    float* op = out + ((size_t)(img0 + img_local) * 64 + oc) * 49;
    #pragma unroll
    for (int mt = 0; mt < 2; mt++) {
      int pxr = tg * 32 + mt * 16 + quad * 4;
      #pragma unroll
      for (int r = 0; r < 4; r++) {
        int px = pxr + r;
        if (px < 49) op[px] = acc[mt][nt][r] + bv;
      }
    }
  }
}

// ---------------- fc1: bit spikes [1024][64ch][7row] x wT[3136,512] -> part ----
__global__ __launch_bounds__(256) void k_fc1(const uint32_t* __restrict__ s3b,
                                             const float* __restrict__ wT,
                                             float* __restrict__ part) {
  __shared__ float xs[16 * 196];
  int tid = threadIdx.x;
  int rowblk = blockIdx.x >> 4;
  int kc     = blockIdx.x & 15;
  int row0 = rowblk * 16;
  int kb   = kc * 196;
  for (int i = tid; i < 448; i += 256) {            // 16r x 4c x 7row words
    int r = i / 28, rem = i - r * 28;
    int c = rem / 7, row = rem - c * 7;
    uint32_t w = s3b[(size_t)(row0 + r) * 448 + (kc * 4 + c) * 7 + row];
    int base = r * 196 + c * 49 + row * 7;
    #pragma unroll
    for (int xq = 0; xq < 7; xq++)
      xs[base + xq] = (float)((w >> xq) & 1u);
  }
  __syncthreads();
  int oc2 = tid * 2;
  float2 acc[16];
  #pragma unroll
  for (int r = 0; r < 16; r++) { acc[r].x = 0.f; acc[r].y = 0.f; }
  const float* wp = wT + (size_t)kb * 512 + oc2;
  const float4* xs4 = (const float4*)xs;
  for (int k4 = 0; k4 < 49; k4++) {
    float2 w0 = *(const float2*)(wp + (size_t)(k4 * 4 + 0) * 512);
    float2 w1 = *(const float2*)(wp + (size_t)(k4 * 4 + 1) * 512);
    float2 w2 = *(const float2*)(wp + (size_t)(k4 * 4 + 2) * 512);
    float2 w3 = *(const float2*)(wp + (size_t)(k4 * 4 + 3) * 512);
    #pragma unroll
    for (int r = 0; r < 16; r++) {
      float4 xv = xs4[r * 49 + k4];
      acc[r].x = fmaf(xv.x, w0.x, acc[r].x);  acc[r].y = fmaf(xv.x, w0.y, acc[r].y);
      acc[r].x = fmaf(xv.y, w1.x, acc[r].x);  acc[r].y = fmaf(xv.y, w1.y, acc[r].y);
      acc[r].x = fmaf(xv.z, w2.x, acc[r].x);  acc[r].y = fmaf(xv.z, w2.y, acc[r].y);
      acc[r].x = fmaf(xv.w, w3.x, acc[r].x);  acc[r].y = fmaf(xv.w, w3.y, acc[r].y);
    }
  }
  #pragma unroll
  for (int r = 0; r < 16; r++) {
    float* o = part + (size_t)kc * 524288 + (size_t)(row0 + r) * 512 + oc2;
    o[0] = acc[r].x; o[1] = acc[r].y;
  }
}

// ---------------- fused: 16-way partial reduce + bias + LIF -> hid u8 ----------
__global__ void k_fc1red_lif(const float* __restrict__ part, const float* __restrict__ bias,
                             unsigned char* __restrict__ hid) {
  int idx = blockIdx.x * 256 + threadIdx.x;
  float bv = bias[idx & 511];
  float v = 0.f;
  #pragma unroll
  for (int t = 0; t < TT; t++) {
    float a = part[t * 65536 + idx];
    #pragma unroll
    for (int j = 1; j < 16; j++) a += part[(size_t)j * 524288 + t * 65536 + idx];
    a += bv;
    v = v + (a - v) * 0.5f;
    unsigned char s = (v >= 1.0f);
    hid[t * 65536 + idx] = s;
    if (s) v = 0.f;
  }
}

// ---------------- fco + mean over T: [8,128,512](u8) -> [128,2] ----------------
__global__ void k_fco(const unsigned char* __restrict__ hid, const float* __restrict__ w,
                      const float* __restrict__ bias, float* __restrict__ out) {
  int b = blockIdx.x, tid = threadIdx.x;
  float a0 = 0.f, a1 = 0.f;
  for (int t = 0; t < TT; t++) {
    const unsigned char* hrow = hid + ((size_t)t * 128 + b) * 512;
    for (int o = tid; o < 512; o += 256) {
      if (hrow[o]) { a0 += w[o]; a1 += w[512 + o]; }
    }
  }
  __shared__ float l0[256], l1[256];
  l0[tid] = a0; l1[tid] = a1; __syncthreads();
  for (int k = 128; k > 0; k >>= 1) {
    if (tid < k) { l0[tid] += l0[tid + k]; l1[tid] += l1[tid + k]; }
    __syncthreads();
  }
  if (tid == 0) {
    out[b * 2 + 0] = l0[0] * 0.125f + bias[0];
    out[b * 2 + 1] = l1[0] * 0.125f + bias[1];
  }
}

extern "C" void kernel_launch(void* const* d_in, const int* in_sizes, int n_in,
                              void* d_out, int out_size, void* d_ws, size_t ws_size,
                              hipStream_t stream) {
  const float* x    = (const float*)d_in[0];
  const float* c1w  = (const float*)d_in[1];
  const float* c1b  = (const float*)d_in[2];
  const float* bn1g = (const float*)d_in[3];
  const float* bn1b = (const float*)d_in[4];
  const float* c2w  = (const float*)d_in[5];
  const float* c2b  = (const float*)d_in[6];
  const float* bn2g = (const float*)d_in[7];
  const float* bn2b = (const float*)d_in[8];
  const float* c3w  = (const float*)d_in[9];
  const float* c3b  = (const float*)d_in[10];
  const float* bn3g = (const float*)d_in[11];
  const float* bn3b = (const float*)d_in[12];
  const float* fc1w = (const float*)d_in[13];
  const float* fc1b = (const float*)d_in[14];
  const float* fcow = (const float*)d_in[15];
  const float* fcob = (const float*)d_in[16];
  float* out = (float*)d_out;

  char* ws = (char*)d_ws;
  // workspace (64.9 MB footprint)
  float*    h1     = (float*)(ws + 0);                 //  6,553,600 (dead after lif1b)
  uint32_t* s1bits = (uint32_t*)(ws + 6553600);        //  2,621,440 (dead after conv2m)
  float*    h2     = (float*)(ws + 19660800);          // 21,233,664 (dead after lif2b)
  uint32_t* s2bits = (uint32_t*)(ws + 40894464);       //  2,359,296 (dead after k_s2T)
  float*    h3     = (float*)(ws + 46202880);          // 12,845,056 (dead after lif3b)
  uint32_t* s3bits = (uint32_t*)(ws + 59047936);       //  1,835,008
  unsigned char* hid = (unsigned char*)(ws + 64356352);//    524,288
  float*    st     = (float*)(ws + 64880640);          //      1,280
  // persistent small weights (gap 60,882,944 .. 62,423,040)
  __bf16*   w2f  = (__bf16*)(ws + 60882944);  // 196,608
  __bf16*   w3f  = (__bf16*)(ws + 61079552);  // 221,184
  uint32_t* s2T  = (uint32_t*)(ws + 61300736);// 663,552 (written after lif2b)
  float*    wT1  = (float*)(ws + 62390272);   // 32,768
  // overlays (lifetimes disjoint):
  float* wTf    = (float*)(ws + 0);         // 6,422,528 in h1 region (after lif1b)
  float* bnpart = (float*)(ws + 9437184);   // 8,192    in s1 region, past s1bits end
  float* f1part = (float*)(ws + 19660800);  // 33,554,432 spans dead h2+s2+h3 (fc1 time)

  prep_wT1   <<<32, 256, 0, stream>>>(c1w, wT1);
  prep_w2frag<<<384, 256, 0, stream>>>(c2w, w2f);
  prep_w3frag<<<432, 256, 0, stream>>>(c3w, w3f);
  k_conv1    <<<dim3(512, 2), 128, 0, stream>>>(x, wT1, c1b, h1);
  k_bnpartial<400><<<dim3(32, 16), 256, 0, stream>>>(h1, 32, 8, bnpart);
  k_bnfinal  <<<32, 64, 0, stream>>>(bnpart, 16, 128.f * 400.f, st, st + 32);
  k_lif1b    <<<320, 256, 0, stream>>>(h1, st, st + 32, bn1g, bn1b, s1bits);
  prep_wTf   <<<dim3(98, 16), 256, 0, stream>>>(fc1w, wTf); // h1 region now free

  k_conv2m   <<<512, 256, 0, stream>>>(s1bits, w2f, c2b, h2);
  k_bnpartial<81><<<dim3(64, 16), 256, 0, stream>>>(h2, 64, 64, bnpart);
  k_bnfinal  <<<64, 64, 0, stream>>>(bnpart, 16, 1024.f * 81.f, st + 64, st + 128);
  k_lifb<9, 9><<<288, 256, 0, stream>>>(h2, st + 64, st + 128, bn2g, bn2b, s2bits, E2_ELEMS);

  k_s2T      <<<1024, 256, 0, stream>>>(s2bits, s2T);
  k_conv3m   <<<512, 256, 0, stream>>>(s2T, w3f, c3b, h3);
  k_bnpartial<49><<<dim3(64, 16), 256, 0, stream>>>(h3, 64, 64, bnpart);
  k_bnfinal  <<<64, 64, 0, stream>>>(bnpart, 16, 1024.f * 49.f, st + 192, st + 256);
  k_lifb<7, 7><<<224, 256, 0, stream>>>(h3, st + 192, st + 256, bn3g, bn3b, s3bits, E3_ELEMS);

  k_fc1      <<<1024, 256, 0, stream>>>(s3bits, wTf, f1part); // h2/s2/h3 now free
  k_fc1red_lif<<<256, 256, 0, stream>>>(f1part, fc1b, hid);
  k_fco      <<<128, 256, 0, stream>>>(hid, fcow, fcob, out);
}